// Round 1
// baseline (2016.956 us; speedup 1.0000x reference)
//
#include <hip/hip_runtime.h>
#include <math.h>

#define D_ 256
#define H_ 4
#define DH_ 64

// ---------------------------------------------------------------------------
// Tiled fp32 GEMM: C[N,M] = A[N,K] * (TRANSB ? B[M,K]^T : B[K,M]), optional ReLU.
// 64x64 tile per 256-thread block, BK=32. All dims are multiples of 64 here.
// ---------------------------------------------------------------------------
template<bool TRANSB, bool RELU>
__global__ __launch_bounds__(256) void gemm_f32(const float* __restrict__ A,
                                                const float* __restrict__ B,
                                                float* __restrict__ C,
                                                int N, int K, int M) {
  __shared__ float As[64][36];   // [n][k], stride 36 floats = 144B (16B-aligned rows)
  __shared__ float Bs[32][68];   // [k][m], stride 68 floats = 272B (16B-aligned rows)
  const int tid = threadIdx.x;
  const int bn = blockIdx.x * 64;
  const int bm = blockIdx.y * 64;
  const int tr = tid >> 4;   // 0..15
  const int tc = tid & 15;   // 0..15
  float acc[4][4] = {};

  for (int k0 = 0; k0 < K; k0 += 32) {
    // A tile 64x32: 512 float4 loads
    #pragma unroll
    for (int i = tid; i < 512; i += 256) {
      int r = i >> 3, c4 = (i & 7) * 4;
      *(float4*)&As[r][c4] = *(const float4*)&A[(size_t)(bn + r) * K + k0 + c4];
    }
    if (TRANSB) {
      // B is [M,K]; Bs[k][m] = B[bm+m][k0+k]
      #pragma unroll
      for (int i = tid; i < 512; i += 256) {
        int m = i >> 3, c4 = (i & 7) * 4;
        float4 w = *(const float4*)&B[(size_t)(bm + m) * K + k0 + c4];
        Bs[c4 + 0][m] = w.x; Bs[c4 + 1][m] = w.y;
        Bs[c4 + 2][m] = w.z; Bs[c4 + 3][m] = w.w;
      }
    } else {
      // B is [K,M]; Bs[k][m] = B[k0+k][bm+m]
      #pragma unroll
      for (int i = tid; i < 512; i += 256) {
        int kk = i >> 4, m4 = (i & 15) * 4;
        *(float4*)&Bs[kk][m4] = *(const float4*)&B[(size_t)(k0 + kk) * M + bm + m4];
      }
    }
    __syncthreads();
    #pragma unroll
    for (int kk = 0; kk < 32; ++kk) {
      float a[4], b[4];
      #pragma unroll
      for (int i = 0; i < 4; ++i) a[i] = As[tr * 4 + i][kk];
      #pragma unroll
      for (int j = 0; j < 4; ++j) b[j] = Bs[kk][tc * 4 + j];
      #pragma unroll
      for (int i = 0; i < 4; ++i)
        #pragma unroll
        for (int j = 0; j < 4; ++j)
          acc[i][j] = fmaf(a[i], b[j], acc[i][j]);
    }
    __syncthreads();
  }
  #pragma unroll
  for (int i = 0; i < 4; ++i) {
    float4 v = make_float4(acc[i][0], acc[i][1], acc[i][2], acc[i][3]);
    if (RELU) {
      v.x = fmaxf(v.x, 0.f); v.y = fmaxf(v.y, 0.f);
      v.z = fmaxf(v.z, 0.f); v.w = fmaxf(v.w, 0.f);
    }
    *(float4*)&C[(size_t)(bn + tr * 4 + i) * M + bm + tc * 4] = v;
  }
}

// ---------------------------------------------------------------------------
// Flash-style fp32 attention. Grid: (T/64, B*H). Block 256 threads.
// Thread t: q-row r = t>>2 of the tile; quad (t&3) owns a 16-wide k-chunk for
// S and a 16-wide d-chunk for the output. Q row held in registers.
// Softmax row stats reduced across the 4-lane quad via __shfl_xor.
// mask is the per-key padding mask [B, Lk]; CAUSAL adds k<=q.
// ---------------------------------------------------------------------------
template<bool CAUSAL>
__global__ __launch_bounds__(256) void attn_f32(const float* __restrict__ Q,
                                                const float* __restrict__ Kp,
                                                const float* __restrict__ Vp,
                                                const float* __restrict__ mask,
                                                float* __restrict__ O,
                                                int T, int Lk) {
  __shared__ float Ks[64][68];
  __shared__ float Vs[64][68];
  __shared__ float Ps[64][68];
  const int tid  = threadIdx.x;
  const int qt   = blockIdx.x;
  const int b    = blockIdx.y >> 2;   // H_ = 4
  const int h    = blockIdx.y & 3;
  const int r    = tid >> 2;
  const int quad = tid & 3;
  const int kb   = quad * 16;
  const int dc   = quad * 16;
  const int qg   = qt * 64 + r;

  float qreg[64];
  {
    const float* qrow = Q + ((size_t)(b * T + qg)) * D_ + h * DH_;
    #pragma unroll
    for (int d4 = 0; d4 < 16; ++d4) {
      float4 t = *(const float4*)&qrow[d4 * 4];
      qreg[d4 * 4 + 0] = t.x; qreg[d4 * 4 + 1] = t.y;
      qreg[d4 * 4 + 2] = t.z; qreg[d4 * 4 + 3] = t.w;
    }
  }
  const float* mrow = mask + (size_t)b * Lk;

  float m = -INFINITY, l = 0.f;
  float acc[16] = {};

  const int nkt = CAUSAL ? (qt + 1) : (Lk / 64);
  for (int kt = 0; kt < nkt; ++kt) {
    const float* kg = Kp + ((size_t)(b * Lk + kt * 64)) * D_ + h * DH_;
    const float* vg = Vp + ((size_t)(b * Lk + kt * 64)) * D_ + h * DH_;
    __syncthreads();   // previous tile's consumers done before overwrite
    #pragma unroll
    for (int i = tid; i < 1024; i += 256) {
      int rr = i >> 4, c4 = (i & 15) * 4;
      *(float4*)&Ks[rr][c4] = *(const float4*)&kg[(size_t)rr * D_ + c4];
      *(float4*)&Vs[rr][c4] = *(const float4*)&vg[(size_t)rr * D_ + c4];
    }
    __syncthreads();

    float p[16];
    float tmax = -INFINITY;
    #pragma unroll
    for (int j = 0; j < 16; ++j) {
      const float* krow = &Ks[kb + j][0];
      float a0 = 0.f, a1 = 0.f, a2 = 0.f, a3 = 0.f;
      #pragma unroll
      for (int d = 0; d < 64; d += 4) {
        float4 kv = *(const float4*)&krow[d];
        a0 = fmaf(qreg[d + 0], kv.x, a0);
        a1 = fmaf(qreg[d + 1], kv.y, a1);
        a2 = fmaf(qreg[d + 2], kv.z, a2);
        a3 = fmaf(qreg[d + 3], kv.w, a3);
      }
      float sv = ((a0 + a1) + (a2 + a3)) * 0.125f;
      int kgidx = kt * 64 + kb + j;
      bool valid = (!CAUSAL || (kgidx <= qg)) && (mrow[kgidx] != 0.f);
      p[j] = valid ? sv : -INFINITY;
      tmax = fmaxf(tmax, p[j]);
    }
    tmax = fmaxf(tmax, __shfl_xor(tmax, 1));
    tmax = fmaxf(tmax, __shfl_xor(tmax, 2));
    float mnew = fmaxf(m, tmax);
    float alpha = (m == mnew) ? 1.f : __expf(m - mnew);  // guards -inf==-inf -> NaN
    float psum = 0.f;
    #pragma unroll
    for (int j = 0; j < 16; ++j) {
      float pv = (p[j] == -INFINITY) ? 0.f : __expf(p[j] - mnew);
      p[j] = pv; psum += pv;
    }
    psum += __shfl_xor(psum, 1);
    psum += __shfl_xor(psum, 2);
    l = l * alpha + psum;
    m = mnew;
    #pragma unroll
    for (int j = 0; j < 16; ++j) acc[j] *= alpha;
    #pragma unroll
    for (int j4 = 0; j4 < 4; ++j4) {
      *(float4*)&Ps[r][kb + j4 * 4] =
          make_float4(p[j4 * 4 + 0], p[j4 * 4 + 1], p[j4 * 4 + 2], p[j4 * 4 + 3]);
    }
    __syncthreads();  // safety: full P tile visible before PV
    #pragma unroll
    for (int k = 0; k < 64; ++k) {
      float pk = Ps[r][k];
      #pragma unroll
      for (int j = 0; j < 16; j += 4) {
        float4 vv = *(const float4*)&Vs[k][dc + j];
        acc[j + 0] = fmaf(pk, vv.x, acc[j + 0]);
        acc[j + 1] = fmaf(pk, vv.y, acc[j + 1]);
        acc[j + 2] = fmaf(pk, vv.z, acc[j + 2]);
        acc[j + 3] = fmaf(pk, vv.w, acc[j + 3]);
      }
    }
  }
  float inv = (l > 0.f) ? (1.f / l) : 0.f;
  float* orow = O + ((size_t)(b * T + qg)) * D_ + h * DH_ + dc;
  #pragma unroll
  for (int j = 0; j < 16; j += 4) {
    *(float4*)&orow[j] = make_float4(acc[j] * inv, acc[j + 1] * inv,
                                     acc[j + 2] * inv, acc[j + 3] * inv);
  }
}

// ---------------------------------------------------------------------------
// out[row] = R[row] + LayerNorm(F[row]) * g + b   (row length 256)
// One wave per row, 4 rows per 256-thread block.
// ---------------------------------------------------------------------------
__global__ __launch_bounds__(256) void ln_res_f32(const float* __restrict__ F,
                                                  const float* __restrict__ R,
                                                  const float* __restrict__ g,
                                                  const float* __restrict__ bt,
                                                  float* __restrict__ out) {
  const int lane = threadIdx.x & 63;
  const int wid  = threadIdx.x >> 6;
  const size_t row  = (size_t)blockIdx.x * 4 + wid;
  const size_t base = row * 256 + (size_t)lane * 4;
  float4 v = *(const float4*)&F[base];
  float s = v.x + v.y + v.z + v.w;
  #pragma unroll
  for (int o = 32; o >= 1; o >>= 1) s += __shfl_xor(s, o);
  float mu = s * (1.f / 256.f);
  float dx = v.x - mu, dy = v.y - mu, dz = v.z - mu, dw = v.w - mu;
  float vr = dx * dx + dy * dy + dz * dz + dw * dw;
  #pragma unroll
  for (int o = 32; o >= 1; o >>= 1) vr += __shfl_xor(vr, o);
  float rstd = rsqrtf(vr * (1.f / 256.f) + 1e-5f);
  float4 g4 = *(const float4*)&g[lane * 4];
  float4 b4 = *(const float4*)&bt[lane * 4];
  float4 r4 = *(const float4*)&R[base];
  float4 o4;
  o4.x = fmaf(dx * rstd, g4.x, b4.x) + r4.x;
  o4.y = fmaf(dy * rstd, g4.y, b4.y) + r4.y;
  o4.z = fmaf(dz * rstd, g4.z, b4.z) + r4.z;
  o4.w = fmaf(dw * rstd, g4.w, b4.w) + r4.w;
  *(float4*)&out[base] = o4;
}

extern "C" void kernel_launch(void* const* d_in, const int* in_sizes, int n_in,
                              void* d_out, int out_size, void* d_ws, size_t ws_size,
                              hipStream_t stream) {
  const float* Xt    = (const float*)d_in[0];
  const float* oMask = (const float*)d_in[1];
  const float* Xe    = (const float*)d_in[2];
  const float* iMask = (const float*)d_in[3];
  const float* Wq1   = (const float*)d_in[4];
  const float* Wk1   = (const float*)d_in[5];
  const float* Wv1   = (const float*)d_in[6];
  const float* Wo1   = (const float*)d_in[7];
  const float* Wq2   = (const float*)d_in[8];
  const float* Wk2   = (const float*)d_in[9];
  const float* Wv2   = (const float*)d_in[10];
  const float* Wo2   = (const float*)d_in[11];
  const float* W1    = (const float*)d_in[12];
  const float* W2    = (const float*)d_in[13];
  const float* g1    = (const float*)d_in[14];
  const float* b1    = (const float*)d_in[15];
  const float* g2    = (const float*)d_in[16];
  const float* b2    = (const float*)d_in[17];
  const float* g3    = (const float*)d_in[18];
  const float* b3    = (const float*)d_in[19];

  const int B = 16, T = 1024, S = 1024;
  const int NT = B * T;                 // 16384 rows
  const size_t SZ = (size_t)NT * 256;   // floats per [NT,256] activation

  // Workspace layout (floats). 6 slots x 16MB = 96MB.
  //  s0: Q1 / P1 / Q2 / P2 / FFN-hidden(start)   s1: K1/K2   s2: V1/V2
  //  s3: attn out (H spans s0..s3 in FFN stage)  s4: Xa / F  s5: Xb
  float* ws = (float*)d_ws;
  float* s0 = ws;
  float* s1 = ws + SZ;
  float* s2 = ws + 2 * SZ;
  float* s3 = ws + 3 * SZ;
  float* s4 = ws + 4 * SZ;
  float* s5 = ws + 5 * SZ;

  dim3 blk(256);
  dim3 gP(NT / 64, 256 / 64);    // (256, 4)
  dim3 gA(T / 64, B * H_);       // (16, 64)
  dim3 gF1(NT / 64, 1024 / 64);  // (256, 16)

  // ---- self-attention block ----
  gemm_f32<true, false><<<gP, blk, 0, stream>>>(Xt, Wq1, s0, NT, 256, 256);
  gemm_f32<true, false><<<gP, blk, 0, stream>>>(Xt, Wk1, s1, NT, 256, 256);
  gemm_f32<true, false><<<gP, blk, 0, stream>>>(Xt, Wv1, s2, NT, 256, 256);
  attn_f32<true><<<gA, blk, 0, stream>>>(s0, s1, s2, oMask, s3, T, T);
  gemm_f32<true, false><<<gP, blk, 0, stream>>>(s3, Wo1, s0, NT, 256, 256);
  ln_res_f32<<<NT / 4, blk, 0, stream>>>(s0, Xt, g1, b1, s4);   // Xa

  // ---- cross-attention block ----
  gemm_f32<true, false><<<gP, blk, 0, stream>>>(s4, Wq2, s0, NT, 256, 256);
  gemm_f32<true, false><<<gP, blk, 0, stream>>>(Xe, Wk2, s1, NT, 256, 256);
  gemm_f32<true, false><<<gP, blk, 0, stream>>>(Xe, Wv2, s2, NT, 256, 256);
  attn_f32<false><<<gA, blk, 0, stream>>>(s0, s1, s2, iMask, s3, T, S);
  gemm_f32<false, false><<<gP, blk, 0, stream>>>(s3, Wo2, s0, NT, 256, 256);  // O @ Wo2 (no T)
  ln_res_f32<<<NT / 4, blk, 0, stream>>>(s0, s4, g2, b2, s5);   // Xb

  // ---- FFN ----
  gemm_f32<true, true><<<gF1, blk, 0, stream>>>(s5, W1, s0, NT, 256, 1024);  // H=relu(Xb@W1^T)
  gemm_f32<true, true><<<gP, blk, 0, stream>>>(s0, W2, s4, NT, 1024, 256);   // F=relu(H@W2^T)
  ln_res_f32<<<NT / 4, blk, 0, stream>>>(s4, s5, g3, b3, (float*)d_out);
}

// Round 2
// 741.652 us; speedup vs baseline: 2.7195x; 2.7195x over previous
//
#include <hip/hip_runtime.h>
#include <math.h>

#define D_ 256
#define H_ 4
#define DH_ 64

typedef __attribute__((ext_vector_type(8))) short bf16x8;
typedef __attribute__((ext_vector_type(4))) short short4v;
typedef __attribute__((ext_vector_type(4))) float f32x4;

__device__ __forceinline__ short f2bf(float x) {
  union { float f; unsigned u; } c; c.f = x;
  unsigned r = (c.u + 0x7fffu + ((c.u >> 16) & 1u)) >> 16;
  return (short)r;
}

// ---------------------------------------------------------------------------
// Tiled fp32 GEMM: C[N,M] = A[N,K] * (TRANSB ? B[M,K]^T : B[K,M]), optional ReLU.
// ---------------------------------------------------------------------------
template<bool TRANSB, bool RELU>
__global__ __launch_bounds__(256) void gemm_f32(const float* __restrict__ A,
                                                const float* __restrict__ B,
                                                float* __restrict__ C,
                                                int N, int K, int M) {
  __shared__ float As[64][36];
  __shared__ float Bs[32][68];
  const int tid = threadIdx.x;
  const int bn = blockIdx.x * 64;
  const int bm = blockIdx.y * 64;
  const int tr = tid >> 4;
  const int tc = tid & 15;
  float acc[4][4] = {};

  for (int k0 = 0; k0 < K; k0 += 32) {
    #pragma unroll
    for (int i = tid; i < 512; i += 256) {
      int r = i >> 3, c4 = (i & 7) * 4;
      *(float4*)&As[r][c4] = *(const float4*)&A[(size_t)(bn + r) * K + k0 + c4];
    }
    if (TRANSB) {
      #pragma unroll
      for (int i = tid; i < 512; i += 256) {
        int m = i >> 3, c4 = (i & 7) * 4;
        float4 w = *(const float4*)&B[(size_t)(bm + m) * K + k0 + c4];
        Bs[c4 + 0][m] = w.x; Bs[c4 + 1][m] = w.y;
        Bs[c4 + 2][m] = w.z; Bs[c4 + 3][m] = w.w;
      }
    } else {
      #pragma unroll
      for (int i = tid; i < 512; i += 256) {
        int kk = i >> 4, m4 = (i & 15) * 4;
        *(float4*)&Bs[kk][m4] = *(const float4*)&B[(size_t)(k0 + kk) * M + bm + m4];
      }
    }
    __syncthreads();
    #pragma unroll
    for (int kk = 0; kk < 32; ++kk) {
      float a[4], b[4];
      #pragma unroll
      for (int i = 0; i < 4; ++i) a[i] = As[tr * 4 + i][kk];
      #pragma unroll
      for (int j = 0; j < 4; ++j) b[j] = Bs[kk][tc * 4 + j];
      #pragma unroll
      for (int i = 0; i < 4; ++i)
        #pragma unroll
        for (int j = 0; j < 4; ++j)
          acc[i][j] = fmaf(a[i], b[j], acc[i][j]);
    }
    __syncthreads();
  }
  #pragma unroll
  for (int i = 0; i < 4; ++i) {
    float4 v = make_float4(acc[i][0], acc[i][1], acc[i][2], acc[i][3]);
    if (RELU) {
      v.x = fmaxf(v.x, 0.f); v.y = fmaxf(v.y, 0.f);
      v.z = fmaxf(v.z, 0.f); v.w = fmaxf(v.w, 0.f);
    }
    *(float4*)&C[(size_t)(bn + tr * 4 + i) * M + bm + tc * 4] = v;
  }
}

// ---------------------------------------------------------------------------
// bf16 MFMA flash attention.
// Grid (T/64, B*H), 256 threads = 4 waves. Wave w owns q rows [qt*64+w*16, +16).
// KV tile = 64 keys. LDS: K row-major bf16 [64][72], V transposed [d=64][k=72],
// P wave-private [16][72]. Stride 72 bf16 (36 dw) -> conflict-free ds_read_b128
// (bank-group (r+g)%8 gets exactly 8 lines).
// mfma_f32_16x16x32_bf16: A lane l: A[l&15][(l>>4)*8+j]; B lane l: B[(l>>4)*8+j][l&15];
// C lane l: col=l&15, row=(l>>4)*4+reg.
// ---------------------------------------------------------------------------
template<bool CAUSAL>
__global__ __launch_bounds__(256) void attn_mfma(const float* __restrict__ Q,
                                                 const float* __restrict__ Kg,
                                                 const float* __restrict__ Vg,
                                                 const float* __restrict__ mask,
                                                 float* __restrict__ O,
                                                 int T, int Lk) {
  __shared__ short Kl[64][72];
  __shared__ short Vt[64][72];
  __shared__ short Pl[4][16][72];
  const int tid = threadIdx.x;
  const int l   = tid & 63;
  const int w   = tid >> 6;
  const int qt  = blockIdx.x;
  const int b   = blockIdx.y >> 2;
  const int h   = blockIdx.y & 3;
  const int r   = l & 15;
  const int g   = l >> 4;
  const int q0  = qt * 64 + w * 16;

  // Q fragments (A-operand), held in registers for the whole kernel.
  bf16x8 qf[2];
  {
    const float* qrow = Q + ((size_t)(b * T + q0 + r)) * D_ + h * DH_;
    #pragma unroll
    for (int kh = 0; kh < 2; ++kh) {
      float4 a = *(const float4*)&qrow[kh * 32 + g * 8];
      float4 c = *(const float4*)&qrow[kh * 32 + g * 8 + 4];
      bf16x8 q8;
      q8[0] = f2bf(a.x); q8[1] = f2bf(a.y); q8[2] = f2bf(a.z); q8[3] = f2bf(a.w);
      q8[4] = f2bf(c.x); q8[5] = f2bf(c.y); q8[6] = f2bf(c.z); q8[7] = f2bf(c.w);
      qf[kh] = q8;
    }
  }

  const float* Kbase = Kg + ((size_t)b * Lk) * D_ + h * DH_;
  const float* Vbase = Vg + ((size_t)b * Lk) * D_ + h * DH_;
  const float* mrow  = mask + (size_t)b * Lk;

  float m[4], lsum[4];
  f32x4 acc[4];  // acc[dt]: O[q rows g*4+i][d cols dt*16+r]
  #pragma unroll
  for (int i = 0; i < 4; ++i) { m[i] = -INFINITY; lsum[i] = 0.f; }
  #pragma unroll
  for (int dt = 0; dt < 4; ++dt) acc[dt] = (f32x4){0.f, 0.f, 0.f, 0.f};

  // staging roles
  const int kr = tid >> 2, kq = tid & 3;      // K: row kr, col group kq
  const int bi = tid & 15, bj = tid >> 4;     // V: d-block bi, k-block bj

  const int nkt = CAUSAL ? (qt + 1) : (Lk / 64);
  for (int kt = 0; kt < nkt; ++kt) {
    __syncthreads();   // prior tile fully consumed
    // ---- stage K tile row-major bf16 ----
    {
      const float* kgr = Kbase + (size_t)(kt * 64 + kr) * D_;
      #pragma unroll
      for (int i = 0; i < 4; ++i) {
        int c = kq * 4 + i * 16;
        float4 v = *(const float4*)&kgr[c];
        short4v s; s[0] = f2bf(v.x); s[1] = f2bf(v.y); s[2] = f2bf(v.z); s[3] = f2bf(v.w);
        *(short4v*)&Kl[kr][c] = s;
      }
    }
    // ---- stage V tile transposed: Vt[d][k] ----
    {
      float4 vv[4];
      #pragma unroll
      for (int i = 0; i < 4; ++i)
        vv[i] = *(const float4*)&Vbase[(size_t)(kt * 64 + bj * 4 + i) * D_ + bi * 4];
      #pragma unroll
      for (int j = 0; j < 4; ++j) {
        short4v s;
        s[0] = f2bf((&vv[0].x)[j]); s[1] = f2bf((&vv[1].x)[j]);
        s[2] = f2bf((&vv[2].x)[j]); s[3] = f2bf((&vv[3].x)[j]);
        *(short4v*)&Vt[bi * 4 + j][bj * 4] = s;
      }
    }
    __syncthreads();

    // ---- QK^T: S[q][k], 4 col-subtiles of 16 k each ----
    f32x4 s[4];
    #pragma unroll
    for (int st = 0; st < 4; ++st) {
      s[st] = (f32x4){0.f, 0.f, 0.f, 0.f};
      #pragma unroll
      for (int kh = 0; kh < 2; ++kh) {
        bf16x8 kf = *(bf16x8*)&Kl[st * 16 + r][kh * 32 + g * 8];
        s[st] = __builtin_amdgcn_mfma_f32_16x16x32_bf16(qf[kh], kf, s[st], 0, 0, 0);
      }
    }

    // ---- mask + scale ----
    float mv[4];
    #pragma unroll
    for (int st = 0; st < 4; ++st) mv[st] = mrow[kt * 64 + st * 16 + r];
    float sc[4][4];  // [st][row i]
    #pragma unroll
    for (int st = 0; st < 4; ++st) {
      int kidx = kt * 64 + st * 16 + r;
      #pragma unroll
      for (int i = 0; i < 4; ++i) {
        float x = s[st][i] * 0.125f;
        bool valid = (mv[st] != 0.f) && (!CAUSAL || kidx <= q0 + g * 4 + i);
        sc[st][i] = valid ? x : -INFINITY;
      }
    }

    // ---- online softmax (per lane: 4 q-rows; reduce over 16 lanes of group) ----
    #pragma unroll
    for (int i = 0; i < 4; ++i) {
      float tm = fmaxf(fmaxf(sc[0][i], sc[1][i]), fmaxf(sc[2][i], sc[3][i]));
      tm = fmaxf(tm, __shfl_xor(tm, 1));
      tm = fmaxf(tm, __shfl_xor(tm, 2));
      tm = fmaxf(tm, __shfl_xor(tm, 4));
      tm = fmaxf(tm, __shfl_xor(tm, 8));
      float mnew  = fmaxf(m[i], tm);
      float alpha = (m[i] == mnew) ? 1.f : __expf(m[i] - mnew);
      float pe[4], psum = 0.f;
      #pragma unroll
      for (int st = 0; st < 4; ++st) {
        pe[st] = __expf(sc[st][i] - mnew);   // -inf -> 0
        psum += pe[st];
      }
      psum += __shfl_xor(psum, 1);
      psum += __shfl_xor(psum, 2);
      psum += __shfl_xor(psum, 4);
      psum += __shfl_xor(psum, 8);
      #pragma unroll
      for (int st = 0; st < 4; ++st)
        Pl[w][g * 4 + i][st * 16 + r] = f2bf(pe[st]);
      lsum[i] = lsum[i] * alpha + psum;
      m[i] = mnew;
      #pragma unroll
      for (int dt = 0; dt < 4; ++dt) acc[dt][i] *= alpha;
    }

    // ---- PV: O += P[16x64] * V[64x64] (P wave-private: no barrier) ----
    #pragma unroll
    for (int kh = 0; kh < 2; ++kh) {
      bf16x8 pf = *(bf16x8*)&Pl[w][r][kh * 32 + g * 8];
      #pragma unroll
      for (int dt = 0; dt < 4; ++dt) {
        bf16x8 vf = *(bf16x8*)&Vt[dt * 16 + r][kh * 32 + g * 8];
        acc[dt] = __builtin_amdgcn_mfma_f32_16x16x32_bf16(pf, vf, acc[dt], 0, 0, 0);
      }
    }
  }

  // ---- epilogue ----
  float inv[4];
  #pragma unroll
  for (int i = 0; i < 4; ++i) inv[i] = (lsum[i] > 0.f) ? (1.f / lsum[i]) : 0.f;
  #pragma unroll
  for (int i = 0; i < 4; ++i) {
    float* orow = O + ((size_t)(b * T + q0 + g * 4 + i)) * D_ + h * DH_;
    #pragma unroll
    for (int dt = 0; dt < 4; ++dt)
      orow[dt * 16 + r] = acc[dt][i] * inv[i];
  }
}

// ---------------------------------------------------------------------------
// out[row] = R[row] + LayerNorm(F[row]) * g + b   (row length 256)
// ---------------------------------------------------------------------------
__global__ __launch_bounds__(256) void ln_res_f32(const float* __restrict__ F,
                                                  const float* __restrict__ R,
                                                  const float* __restrict__ g,
                                                  const float* __restrict__ bt,
                                                  float* __restrict__ out) {
  const int lane = threadIdx.x & 63;
  const int wid  = threadIdx.x >> 6;
  const size_t row  = (size_t)blockIdx.x * 4 + wid;
  const size_t base = row * 256 + (size_t)lane * 4;
  float4 v = *(const float4*)&F[base];
  float s = v.x + v.y + v.z + v.w;
  #pragma unroll
  for (int o = 32; o >= 1; o >>= 1) s += __shfl_xor(s, o);
  float mu = s * (1.f / 256.f);
  float dx = v.x - mu, dy = v.y - mu, dz = v.z - mu, dw = v.w - mu;
  float vr = dx * dx + dy * dy + dz * dz + dw * dw;
  #pragma unroll
  for (int o = 32; o >= 1; o >>= 1) vr += __shfl_xor(vr, o);
  float rstd = rsqrtf(vr * (1.f / 256.f) + 1e-5f);
  float4 g4 = *(const float4*)&g[lane * 4];
  float4 b4 = *(const float4*)&bt[lane * 4];
  float4 r4 = *(const float4*)&R[base];
  float4 o4;
  o4.x = fmaf(dx * rstd, g4.x, b4.x) + r4.x;
  o4.y = fmaf(dy * rstd, g4.y, b4.y) + r4.y;
  o4.z = fmaf(dz * rstd, g4.z, b4.z) + r4.z;
  o4.w = fmaf(dw * rstd, g4.w, b4.w) + r4.w;
  *(float4*)&out[base] = o4;
}

extern "C" void kernel_launch(void* const* d_in, const int* in_sizes, int n_in,
                              void* d_out, int out_size, void* d_ws, size_t ws_size,
                              hipStream_t stream) {
  const float* Xt    = (const float*)d_in[0];
  const float* oMask = (const float*)d_in[1];
  const float* Xe    = (const float*)d_in[2];
  const float* iMask = (const float*)d_in[3];
  const float* Wq1   = (const float*)d_in[4];
  const float* Wk1   = (const float*)d_in[5];
  const float* Wv1   = (const float*)d_in[6];
  const float* Wo1   = (const float*)d_in[7];
  const float* Wq2   = (const float*)d_in[8];
  const float* Wk2   = (const float*)d_in[9];
  const float* Wv2   = (const float*)d_in[10];
  const float* Wo2   = (const float*)d_in[11];
  const float* W1    = (const float*)d_in[12];
  const float* W2    = (const float*)d_in[13];
  const float* g1    = (const float*)d_in[14];
  const float* b1    = (const float*)d_in[15];
  const float* g2    = (const float*)d_in[16];
  const float* b2    = (const float*)d_in[17];
  const float* g3    = (const float*)d_in[18];
  const float* b3    = (const float*)d_in[19];

  const int B = 16, T = 1024, S = 1024;
  const int NT = B * T;
  const size_t SZ = (size_t)NT * 256;

  float* ws = (float*)d_ws;
  float* s0 = ws;
  float* s1 = ws + SZ;
  float* s2 = ws + 2 * SZ;
  float* s3 = ws + 3 * SZ;
  float* s4 = ws + 4 * SZ;
  float* s5 = ws + 5 * SZ;

  dim3 blk(256);
  dim3 gP(NT / 64, 256 / 64);
  dim3 gA(T / 64, B * H_);
  dim3 gF1(NT / 64, 1024 / 64);

  // ---- self-attention block ----
  gemm_f32<true, false><<<gP, blk, 0, stream>>>(Xt, Wq1, s0, NT, 256, 256);
  gemm_f32<true, false><<<gP, blk, 0, stream>>>(Xt, Wk1, s1, NT, 256, 256);
  gemm_f32<true, false><<<gP, blk, 0, stream>>>(Xt, Wv1, s2, NT, 256, 256);
  attn_mfma<true><<<gA, blk, 0, stream>>>(s0, s1, s2, oMask, s3, T, T);
  gemm_f32<true, false><<<gP, blk, 0, stream>>>(s3, Wo1, s0, NT, 256, 256);
  ln_res_f32<<<NT / 4, blk, 0, stream>>>(s0, Xt, g1, b1, s4);

  // ---- cross-attention block ----
  gemm_f32<true, false><<<gP, blk, 0, stream>>>(s4, Wq2, s0, NT, 256, 256);
  gemm_f32<true, false><<<gP, blk, 0, stream>>>(Xe, Wk2, s1, NT, 256, 256);
  gemm_f32<true, false><<<gP, blk, 0, stream>>>(Xe, Wv2, s2, NT, 256, 256);
  attn_mfma<false><<<gA, blk, 0, stream>>>(s0, s1, s2, iMask, s3, T, S);
  gemm_f32<false, false><<<gP, blk, 0, stream>>>(s3, Wo2, s0, NT, 256, 256);
  ln_res_f32<<<NT / 4, blk, 0, stream>>>(s0, s4, g2, b2, s5);

  // ---- FFN ----
  gemm_f32<true, true><<<gF1, blk, 0, stream>>>(s5, W1, s0, NT, 256, 1024);
  gemm_f32<true, true><<<gP, blk, 0, stream>>>(s0, W2, s4, NT, 1024, 256);
  ln_res_f32<<<NT / 4, blk, 0, stream>>>(s4, s5, g3, b3, (float*)d_out);
}

// Round 3
// 418.550 us; speedup vs baseline: 4.8189x; 1.7720x over previous
//
#include <hip/hip_runtime.h>
#include <math.h>

#define D_ 256
#define H_ 4
#define DH_ 64

typedef __attribute__((ext_vector_type(8))) short bf16x8;
typedef __attribute__((ext_vector_type(4))) short short4v;
typedef __attribute__((ext_vector_type(4))) float f32x4;

__device__ __forceinline__ short f2bf(float x) {
  union { float f; unsigned u; } c; c.f = x;
  unsigned r = (c.u + 0x7fffu + ((c.u >> 16) & 1u)) >> 16;
  return (short)r;
}

// ---------------------------------------------------------------------------
// bf16 MFMA GEMM: C[N,M] = A[N,K] * (TRANSB ? B[M,K]^T : B[K,M]), optional ReLU.
// fp32 inputs converted to bf16 during LDS staging; fp32 accumulate; fp32 C.
// 128x128 tile, BK=64, 256 threads = 4 waves in 2x2; each wave 64x64 out
// (4x4 fragments of mfma_f32_16x16x32_bf16). LDS stride 72 bf16 = 144 B:
// fragment ds_read_b128 start bank = 4*row mod 32 -> 2-way (free).
// ---------------------------------------------------------------------------
template<bool TRANSB, bool RELU>
__global__ __launch_bounds__(256) void gemm_bf16(const float* __restrict__ A,
                                                 const float* __restrict__ B,
                                                 float* __restrict__ C,
                                                 int N, int K, int M) {
  __shared__ short Al[128][72];
  __shared__ short Bl[128][72];
  const int tid = threadIdx.x;
  const int w   = tid >> 6;
  const int l   = tid & 63;
  const int bn  = blockIdx.x * 128;
  const int bm  = blockIdx.y * 128;
  const int wm  = (w >> 1) * 64;
  const int wn  = (w & 1) * 64;
  const int fr  = l & 15;
  const int fg  = l >> 4;

  f32x4 acc[4][4];
  #pragma unroll
  for (int mi = 0; mi < 4; ++mi)
    #pragma unroll
    for (int ni = 0; ni < 4; ++ni) acc[mi][ni] = (f32x4){0.f, 0.f, 0.f, 0.f};

  const int sr = tid >> 1;           // 0..127: staging row
  const int sc = (tid & 1) * 32;     // col half

  for (int k0 = 0; k0 < K; k0 += 64) {
    __syncthreads();
    // ---- stage A[bn..+128][k0..+64] -> bf16 ----
    {
      const float* arow = A + (size_t)(bn + sr) * K + k0 + sc;
      #pragma unroll
      for (int i = 0; i < 8; ++i) {
        float4 v = *(const float4*)&arow[i * 4];
        short4v s; s[0] = f2bf(v.x); s[1] = f2bf(v.y); s[2] = f2bf(v.z); s[3] = f2bf(v.w);
        *(short4v*)&Al[sr][sc + i * 4] = s;
      }
    }
    // ---- stage B -> Bl[n][k] ----
    if (TRANSB) {
      const float* brow = B + (size_t)(bm + sr) * K + k0 + sc;
      #pragma unroll
      for (int i = 0; i < 8; ++i) {
        float4 v = *(const float4*)&brow[i * 4];
        short4v s; s[0] = f2bf(v.x); s[1] = f2bf(v.y); s[2] = f2bf(v.z); s[3] = f2bf(v.w);
        *(short4v*)&Bl[sr][sc + i * 4] = s;
      }
    } else {
      #pragma unroll
      for (int i = 0; i < 8; ++i) {
        int idx = tid + i * 256;
        int kk = idx >> 5;            // 0..63
        int c4 = (idx & 31) * 4;      // 0..124
        float4 v = *(const float4*)&B[(size_t)(k0 + kk) * M + bm + c4];
        Bl[c4 + 0][kk] = f2bf(v.x);
        Bl[c4 + 1][kk] = f2bf(v.y);
        Bl[c4 + 2][kk] = f2bf(v.z);
        Bl[c4 + 3][kk] = f2bf(v.w);
      }
    }
    __syncthreads();

    #pragma unroll
    for (int kh = 0; kh < 2; ++kh) {
      bf16x8 af[4], bfr[4];
      #pragma unroll
      for (int mi = 0; mi < 4; ++mi)
        af[mi] = *(bf16x8*)&Al[wm + mi * 16 + fr][kh * 32 + fg * 8];
      #pragma unroll
      for (int ni = 0; ni < 4; ++ni)
        bfr[ni] = *(bf16x8*)&Bl[wn + ni * 16 + fr][kh * 32 + fg * 8];
      #pragma unroll
      for (int mi = 0; mi < 4; ++mi)
        #pragma unroll
        for (int ni = 0; ni < 4; ++ni)
          acc[mi][ni] = __builtin_amdgcn_mfma_f32_16x16x32_bf16(af[mi], bfr[ni], acc[mi][ni], 0, 0, 0);
    }
  }

  // ---- epilogue: C col = l&15, row = (l>>4)*4 + reg ----
  #pragma unroll
  for (int mi = 0; mi < 4; ++mi) {
    #pragma unroll
    for (int reg = 0; reg < 4; ++reg) {
      float* crow = C + (size_t)(bn + wm + mi * 16 + fg * 4 + reg) * M + bm + wn;
      #pragma unroll
      for (int ni = 0; ni < 4; ++ni) {
        float v = acc[mi][ni][reg];
        if (RELU) v = fmaxf(v, 0.f);
        crow[ni * 16 + fr] = v;
      }
    }
  }
}

// ---------------------------------------------------------------------------
// bf16 MFMA flash attention (unchanged from R1).
// ---------------------------------------------------------------------------
template<bool CAUSAL>
__global__ __launch_bounds__(256) void attn_mfma(const float* __restrict__ Q,
                                                 const float* __restrict__ Kg,
                                                 const float* __restrict__ Vg,
                                                 const float* __restrict__ mask,
                                                 float* __restrict__ O,
                                                 int T, int Lk) {
  __shared__ short Kl[64][72];
  __shared__ short Vt[64][72];
  __shared__ short Pl[4][16][72];
  const int tid = threadIdx.x;
  const int l   = tid & 63;
  const int w   = tid >> 6;
  const int qt  = blockIdx.x;
  const int b   = blockIdx.y >> 2;
  const int h   = blockIdx.y & 3;
  const int r   = l & 15;
  const int g   = l >> 4;
  const int q0  = qt * 64 + w * 16;

  bf16x8 qf[2];
  {
    const float* qrow = Q + ((size_t)(b * T + q0 + r)) * D_ + h * DH_;
    #pragma unroll
    for (int kh = 0; kh < 2; ++kh) {
      float4 a = *(const float4*)&qrow[kh * 32 + g * 8];
      float4 c = *(const float4*)&qrow[kh * 32 + g * 8 + 4];
      bf16x8 q8;
      q8[0] = f2bf(a.x); q8[1] = f2bf(a.y); q8[2] = f2bf(a.z); q8[3] = f2bf(a.w);
      q8[4] = f2bf(c.x); q8[5] = f2bf(c.y); q8[6] = f2bf(c.z); q8[7] = f2bf(c.w);
      qf[kh] = q8;
    }
  }

  const float* Kbase = Kg + ((size_t)b * Lk) * D_ + h * DH_;
  const float* Vbase = Vg + ((size_t)b * Lk) * D_ + h * DH_;
  const float* mrow  = mask + (size_t)b * Lk;

  float m[4], lsum[4];
  f32x4 acc[4];
  #pragma unroll
  for (int i = 0; i < 4; ++i) { m[i] = -INFINITY; lsum[i] = 0.f; }
  #pragma unroll
  for (int dt = 0; dt < 4; ++dt) acc[dt] = (f32x4){0.f, 0.f, 0.f, 0.f};

  const int kr = tid >> 2, kq = tid & 3;
  const int bi = tid & 15, bj = tid >> 4;

  const int nkt = CAUSAL ? (qt + 1) : (Lk / 64);
  for (int kt = 0; kt < nkt; ++kt) {
    __syncthreads();
    {
      const float* kgr = Kbase + (size_t)(kt * 64 + kr) * D_;
      #pragma unroll
      for (int i = 0; i < 4; ++i) {
        int c = kq * 4 + i * 16;
        float4 v = *(const float4*)&kgr[c];
        short4v s; s[0] = f2bf(v.x); s[1] = f2bf(v.y); s[2] = f2bf(v.z); s[3] = f2bf(v.w);
        *(short4v*)&Kl[kr][c] = s;
      }
    }
    {
      float4 vv[4];
      #pragma unroll
      for (int i = 0; i < 4; ++i)
        vv[i] = *(const float4*)&Vbase[(size_t)(kt * 64 + bj * 4 + i) * D_ + bi * 4];
      #pragma unroll
      for (int j = 0; j < 4; ++j) {
        short4v s;
        s[0] = f2bf((&vv[0].x)[j]); s[1] = f2bf((&vv[1].x)[j]);
        s[2] = f2bf((&vv[2].x)[j]); s[3] = f2bf((&vv[3].x)[j]);
        *(short4v*)&Vt[bi * 4 + j][bj * 4] = s;
      }
    }
    __syncthreads();

    f32x4 s[4];
    #pragma unroll
    for (int st = 0; st < 4; ++st) {
      s[st] = (f32x4){0.f, 0.f, 0.f, 0.f};
      #pragma unroll
      for (int kh = 0; kh < 2; ++kh) {
        bf16x8 kf = *(bf16x8*)&Kl[st * 16 + r][kh * 32 + g * 8];
        s[st] = __builtin_amdgcn_mfma_f32_16x16x32_bf16(qf[kh], kf, s[st], 0, 0, 0);
      }
    }

    float mv[4];
    #pragma unroll
    for (int st = 0; st < 4; ++st) mv[st] = mrow[kt * 64 + st * 16 + r];
    float sc[4][4];
    #pragma unroll
    for (int st = 0; st < 4; ++st) {
      int kidx = kt * 64 + st * 16 + r;
      #pragma unroll
      for (int i = 0; i < 4; ++i) {
        float x = s[st][i] * 0.125f;
        bool valid = (mv[st] != 0.f) && (!CAUSAL || kidx <= q0 + g * 4 + i);
        sc[st][i] = valid ? x : -INFINITY;
      }
    }

    #pragma unroll
    for (int i = 0; i < 4; ++i) {
      float tm = fmaxf(fmaxf(sc[0][i], sc[1][i]), fmaxf(sc[2][i], sc[3][i]));
      tm = fmaxf(tm, __shfl_xor(tm, 1));
      tm = fmaxf(tm, __shfl_xor(tm, 2));
      tm = fmaxf(tm, __shfl_xor(tm, 4));
      tm = fmaxf(tm, __shfl_xor(tm, 8));
      float mnew  = fmaxf(m[i], tm);
      float alpha = (m[i] == mnew) ? 1.f : __expf(m[i] - mnew);
      float pe[4], psum = 0.f;
      #pragma unroll
      for (int st = 0; st < 4; ++st) {
        pe[st] = __expf(sc[st][i] - mnew);
        psum += pe[st];
      }
      psum += __shfl_xor(psum, 1);
      psum += __shfl_xor(psum, 2);
      psum += __shfl_xor(psum, 4);
      psum += __shfl_xor(psum, 8);
      #pragma unroll
      for (int st = 0; st < 4; ++st)
        Pl[w][g * 4 + i][st * 16 + r] = f2bf(pe[st]);
      lsum[i] = lsum[i] * alpha + psum;
      m[i] = mnew;
      #pragma unroll
      for (int dt = 0; dt < 4; ++dt) acc[dt][i] *= alpha;
    }

    #pragma unroll
    for (int kh = 0; kh < 2; ++kh) {
      bf16x8 pf = *(bf16x8*)&Pl[w][r][kh * 32 + g * 8];
      #pragma unroll
      for (int dt = 0; dt < 4; ++dt) {
        bf16x8 vf = *(bf16x8*)&Vt[dt * 16 + r][kh * 32 + g * 8];
        acc[dt] = __builtin_amdgcn_mfma_f32_16x16x32_bf16(pf, vf, acc[dt], 0, 0, 0);
      }
    }
  }

  float inv[4];
  #pragma unroll
  for (int i = 0; i < 4; ++i) inv[i] = (lsum[i] > 0.f) ? (1.f / lsum[i]) : 0.f;
  #pragma unroll
  for (int i = 0; i < 4; ++i) {
    float* orow = O + ((size_t)(b * T + q0 + g * 4 + i)) * D_ + h * DH_;
    #pragma unroll
    for (int dt = 0; dt < 4; ++dt)
      orow[dt * 16 + r] = acc[dt][i] * inv[i];
  }
}

// ---------------------------------------------------------------------------
// out[row] = R[row] + LayerNorm(F[row]) * g + b   (row length 256)
// ---------------------------------------------------------------------------
__global__ __launch_bounds__(256) void ln_res_f32(const float* __restrict__ F,
                                                  const float* __restrict__ R,
                                                  const float* __restrict__ g,
                                                  const float* __restrict__ bt,
                                                  float* __restrict__ out) {
  const int lane = threadIdx.x & 63;
  const int wid  = threadIdx.x >> 6;
  const size_t row  = (size_t)blockIdx.x * 4 + wid;
  const size_t base = row * 256 + (size_t)lane * 4;
  float4 v = *(const float4*)&F[base];
  float s = v.x + v.y + v.z + v.w;
  #pragma unroll
  for (int o = 32; o >= 1; o >>= 1) s += __shfl_xor(s, o);
  float mu = s * (1.f / 256.f);
  float dx = v.x - mu, dy = v.y - mu, dz = v.z - mu, dw = v.w - mu;
  float vr = dx * dx + dy * dy + dz * dz + dw * dw;
  #pragma unroll
  for (int o = 32; o >= 1; o >>= 1) vr += __shfl_xor(vr, o);
  float rstd = rsqrtf(vr * (1.f / 256.f) + 1e-5f);
  float4 g4 = *(const float4*)&g[lane * 4];
  float4 b4 = *(const float4*)&bt[lane * 4];
  float4 r4 = *(const float4*)&R[base];
  float4 o4;
  o4.x = fmaf(dx * rstd, g4.x, b4.x) + r4.x;
  o4.y = fmaf(dy * rstd, g4.y, b4.y) + r4.y;
  o4.z = fmaf(dz * rstd, g4.z, b4.z) + r4.z;
  o4.w = fmaf(dw * rstd, g4.w, b4.w) + r4.w;
  *(float4*)&out[base] = o4;
}

extern "C" void kernel_launch(void* const* d_in, const int* in_sizes, int n_in,
                              void* d_out, int out_size, void* d_ws, size_t ws_size,
                              hipStream_t stream) {
  const float* Xt    = (const float*)d_in[0];
  const float* oMask = (const float*)d_in[1];
  const float* Xe    = (const float*)d_in[2];
  const float* iMask = (const float*)d_in[3];
  const float* Wq1   = (const float*)d_in[4];
  const float* Wk1   = (const float*)d_in[5];
  const float* Wv1   = (const float*)d_in[6];
  const float* Wo1   = (const float*)d_in[7];
  const float* Wq2   = (const float*)d_in[8];
  const float* Wk2   = (const float*)d_in[9];
  const float* Wv2   = (const float*)d_in[10];
  const float* Wo2   = (const float*)d_in[11];
  const float* W1    = (const float*)d_in[12];
  const float* W2    = (const float*)d_in[13];
  const float* g1    = (const float*)d_in[14];
  const float* b1    = (const float*)d_in[15];
  const float* g2    = (const float*)d_in[16];
  const float* b2    = (const float*)d_in[17];
  const float* g3    = (const float*)d_in[18];
  const float* b3    = (const float*)d_in[19];

  const int B = 16, T = 1024, S = 1024;
  const int NT = B * T;
  const size_t SZ = (size_t)NT * 256;

  float* ws = (float*)d_ws;
  float* s0 = ws;
  float* s1 = ws + SZ;
  float* s2 = ws + 2 * SZ;
  float* s3 = ws + 3 * SZ;
  float* s4 = ws + 4 * SZ;
  float* s5 = ws + 5 * SZ;

  dim3 blk(256);
  dim3 gP(NT / 128, 256 / 128);     // (128, 2)
  dim3 gA(T / 64, B * H_);          // (16, 64)
  dim3 gF1(NT / 128, 1024 / 128);   // (128, 8)

  // ---- self-attention block ----
  gemm_bf16<true, false><<<gP, blk, 0, stream>>>(Xt, Wq1, s0, NT, 256, 256);
  gemm_bf16<true, false><<<gP, blk, 0, stream>>>(Xt, Wk1, s1, NT, 256, 256);
  gemm_bf16<true, false><<<gP, blk, 0, stream>>>(Xt, Wv1, s2, NT, 256, 256);
  attn_mfma<true><<<gA, blk, 0, stream>>>(s0, s1, s2, oMask, s3, T, T);
  gemm_bf16<true, false><<<gP, blk, 0, stream>>>(s3, Wo1, s0, NT, 256, 256);
  ln_res_f32<<<NT / 4, blk, 0, stream>>>(s0, Xt, g1, b1, s4);

  // ---- cross-attention block ----
  gemm_bf16<true, false><<<gP, blk, 0, stream>>>(s4, Wq2, s0, NT, 256, 256);
  gemm_bf16<true, false><<<gP, blk, 0, stream>>>(Xe, Wk2, s1, NT, 256, 256);
  gemm_bf16<true, false><<<gP, blk, 0, stream>>>(Xe, Wv2, s2, NT, 256, 256);
  attn_mfma<false><<<gA, blk, 0, stream>>>(s0, s1, s2, iMask, s3, T, S);
  gemm_bf16<false, false><<<gP, blk, 0, stream>>>(s3, Wo2, s0, NT, 256, 256);
  ln_res_f32<<<NT / 4, blk, 0, stream>>>(s0, s4, g2, b2, s5);

  // ---- FFN ----
  gemm_bf16<true, true><<<gF1, blk, 0, stream>>>(s5, W1, s0, NT, 256, 1024);
  gemm_bf16<true, true><<<gP, blk, 0, stream>>>(s0, W2, s4, NT, 1024, 256);
  ln_res_f32<<<NT / 4, blk, 0, stream>>>(s4, s5, g3, b3, (float*)d_out);
}

// Round 4
// 340.688 us; speedup vs baseline: 5.9202x; 1.2285x over previous
//
#include <hip/hip_runtime.h>
#include <math.h>

#define D_ 256
#define H_ 4
#define DH_ 64

typedef __attribute__((ext_vector_type(8))) short bf16x8;
typedef __attribute__((ext_vector_type(4))) short short4v;
typedef __attribute__((ext_vector_type(4))) float f32x4;

__device__ __forceinline__ short f2bf(float x) {
  union { float f; unsigned u; } c; c.f = x;
  unsigned r = (c.u + 0x7fffu + ((c.u >> 16) & 1u)) >> 16;
  return (short)r;
}

// ---------------------------------------------------------------------------
// MFMA GEMM: C[N,M] = A[N,K] * (TRANSB ? B[M,K]^T : B[K,M]), optional ReLU.
// A: fp32 (converted during staging) or bf16 (direct copy). B: fp32 weights.
// C: fp32 or bf16. 128x128 tile, BK=64, 4 waves 2x2, each 4x4 frags of
// mfma_f32_16x16x32_bf16. LDS stride 72 bf16.
// ---------------------------------------------------------------------------
template<bool ABF16, bool TRANSB, bool RELU, bool CBF16>
__global__ __launch_bounds__(256) void gemm_mfma(const void* __restrict__ Av,
                                                 const float* __restrict__ B,
                                                 void* __restrict__ Cv,
                                                 int N, int K, int M) {
  __shared__ short Al[128][72];
  __shared__ short Bl[128][72];
  const int tid = threadIdx.x;
  const int w   = tid >> 6;
  const int l   = tid & 63;
  const int bn  = blockIdx.x * 128;
  const int bm  = blockIdx.y * 128;
  const int wm  = (w >> 1) * 64;
  const int wn  = (w & 1) * 64;
  const int fr  = l & 15;
  const int fg  = l >> 4;

  f32x4 acc[4][4];
  #pragma unroll
  for (int mi = 0; mi < 4; ++mi)
    #pragma unroll
    for (int ni = 0; ni < 4; ++ni) acc[mi][ni] = (f32x4){0.f, 0.f, 0.f, 0.f};

  const int sr = tid >> 1;
  const int sc = (tid & 1) * 32;

  for (int k0 = 0; k0 < K; k0 += 64) {
    __syncthreads();
    if (ABF16) {
      const short* arow = (const short*)Av + (size_t)(bn + sr) * K + k0 + sc;
      #pragma unroll
      for (int i = 0; i < 4; ++i)
        *(bf16x8*)&Al[sr][sc + i * 8] = *(const bf16x8*)&arow[i * 8];
    } else {
      const float* arow = (const float*)Av + (size_t)(bn + sr) * K + k0 + sc;
      #pragma unroll
      for (int i = 0; i < 8; ++i) {
        float4 v = *(const float4*)&arow[i * 4];
        short4v s; s[0] = f2bf(v.x); s[1] = f2bf(v.y); s[2] = f2bf(v.z); s[3] = f2bf(v.w);
        *(short4v*)&Al[sr][sc + i * 4] = s;
      }
    }
    if (TRANSB) {
      const float* brow = B + (size_t)(bm + sr) * K + k0 + sc;
      #pragma unroll
      for (int i = 0; i < 8; ++i) {
        float4 v = *(const float4*)&brow[i * 4];
        short4v s; s[0] = f2bf(v.x); s[1] = f2bf(v.y); s[2] = f2bf(v.z); s[3] = f2bf(v.w);
        *(short4v*)&Bl[sr][sc + i * 4] = s;
      }
    } else {
      #pragma unroll
      for (int i = 0; i < 8; ++i) {
        int idx = tid + i * 256;
        int kk = idx >> 5;
        int c4 = (idx & 31) * 4;
        float4 v = *(const float4*)&B[(size_t)(k0 + kk) * M + bm + c4];
        Bl[c4 + 0][kk] = f2bf(v.x);
        Bl[c4 + 1][kk] = f2bf(v.y);
        Bl[c4 + 2][kk] = f2bf(v.z);
        Bl[c4 + 3][kk] = f2bf(v.w);
      }
    }
    __syncthreads();

    #pragma unroll
    for (int kh = 0; kh < 2; ++kh) {
      bf16x8 af[4], bfr[4];
      #pragma unroll
      for (int mi = 0; mi < 4; ++mi)
        af[mi] = *(bf16x8*)&Al[wm + mi * 16 + fr][kh * 32 + fg * 8];
      #pragma unroll
      for (int ni = 0; ni < 4; ++ni)
        bfr[ni] = *(bf16x8*)&Bl[wn + ni * 16 + fr][kh * 32 + fg * 8];
      #pragma unroll
      for (int mi = 0; mi < 4; ++mi)
        #pragma unroll
        for (int ni = 0; ni < 4; ++ni)
          acc[mi][ni] = __builtin_amdgcn_mfma_f32_16x16x32_bf16(af[mi], bfr[ni], acc[mi][ni], 0, 0, 0);
    }
  }

  #pragma unroll
  for (int mi = 0; mi < 4; ++mi) {
    #pragma unroll
    for (int reg = 0; reg < 4; ++reg) {
      size_t rowbase = (size_t)(bn + wm + mi * 16 + fg * 4 + reg) * M + bm + wn;
      #pragma unroll
      for (int ni = 0; ni < 4; ++ni) {
        float v = acc[mi][ni][reg];
        if (RELU) v = fmaxf(v, 0.f);
        if (CBF16) ((short*)Cv)[rowbase + ni * 16 + fr] = f2bf(v);
        else       ((float*)Cv)[rowbase + ni * 16 + fr] = v;
      }
    }
  }
}

// ---------------------------------------------------------------------------
// bf16 MFMA flash attention, swapped-QK^T softmax.
// Grid (T/64, B*H), 4 waves; wave w: q rows q0=qt*64+w*16 (one per lane r).
// Swapped QKT: S^T frag -> lane r owns q-row r; k = st*16 + g*4 + reg.
// Row reduce: 15 in-lane ops + shfl_xor(16,32). P -> LDS (short4 writes) ->
// A-frag for PV. Padding mask staged as additive bias in LDS; causal compare
// only on boundary tile kt==qt.
// ---------------------------------------------------------------------------
template<bool CAUSAL>
__global__ __launch_bounds__(256) void attn_mfma(const short* __restrict__ Q,
                                                 const short* __restrict__ Kg,
                                                 const short* __restrict__ Vg,
                                                 const float* __restrict__ mask,
                                                 short* __restrict__ O,
                                                 int T, int Lk) {
  __shared__ short Kl[64][72];
  __shared__ short Vt[64][72];
  __shared__ short Pl[4][16][72];
  __shared__ float Mb[64];
  const int tid = threadIdx.x;
  const int l   = tid & 63;
  const int w   = tid >> 6;
  const int qt  = blockIdx.x;
  const int b   = blockIdx.y >> 2;
  const int h   = blockIdx.y & 3;
  const int r   = l & 15;
  const int g   = l >> 4;
  const int q0  = qt * 64 + w * 16;

  bf16x8 qf[2];
  {
    const short* qrow = Q + ((size_t)(b * T + q0 + r)) * D_ + h * DH_;
    qf[0] = *(const bf16x8*)&qrow[g * 8];
    qf[1] = *(const bf16x8*)&qrow[32 + g * 8];
  }

  const short* Kbase = Kg + (size_t)b * Lk * D_ + h * DH_;
  const short* Vbase = Vg + (size_t)b * Lk * D_ + h * DH_;
  const float* mrow  = mask + (size_t)b * Lk;

  float m = -1e30f, lsum = 0.f;
  f32x4 acc[4];
  #pragma unroll
  for (int dt = 0; dt < 4; ++dt) acc[dt] = (f32x4){0.f, 0.f, 0.f, 0.f};

  const int kr = tid >> 2, kq = (tid & 3) * 16;
  const int bi = tid & 15, bj = tid >> 4;

  const int nkt = CAUSAL ? (qt + 1) : (Lk / 64);
  for (int kt = 0; kt < nkt; ++kt) {
    __syncthreads();
    if (tid < 64) {
      float v = mrow[kt * 64 + tid];
      Mb[tid] = (v != 0.f) ? 0.f : -1e30f;
    }
    {  // K: direct bf16 copy
      const short* kgr = Kbase + (size_t)(kt * 64 + kr) * D_ + kq;
      *(bf16x8*)&Kl[kr][kq]     = *(const bf16x8*)&kgr[0];
      *(bf16x8*)&Kl[kr][kq + 8] = *(const bf16x8*)&kgr[8];
    }
    {  // V: 4x4 in-reg transpose
      short4v vv[4];
      #pragma unroll
      for (int i = 0; i < 4; ++i)
        vv[i] = *(const short4v*)&Vbase[(size_t)(kt * 64 + bj * 4 + i) * D_ + bi * 4];
      #pragma unroll
      for (int j = 0; j < 4; ++j) {
        short4v s; s[0] = vv[0][j]; s[1] = vv[1][j]; s[2] = vv[2][j]; s[3] = vv[3][j];
        *(short4v*)&Vt[bi * 4 + j][bj * 4] = s;
      }
    }
    __syncthreads();

    // ---- swapped QK^T: D[k][q], lane: q-row = r, k = st*16 + g*4 + reg ----
    f32x4 sfr[4];
    #pragma unroll
    for (int st = 0; st < 4; ++st) {
      sfr[st] = (f32x4){0.f, 0.f, 0.f, 0.f};
      #pragma unroll
      for (int kh = 0; kh < 2; ++kh) {
        bf16x8 kf = *(bf16x8*)&Kl[st * 16 + r][kh * 32 + g * 8];
        sfr[st] = __builtin_amdgcn_mfma_f32_16x16x32_bf16(kf, qf[kh], sfr[st], 0, 0, 0);
      }
    }

    float sc[4][4];
    #pragma unroll
    for (int st = 0; st < 4; ++st) {
      float4 mb = *(float4*)&Mb[st * 16 + g * 4];
      #pragma unroll
      for (int reg = 0; reg < 4; ++reg)
        sc[st][reg] = fmaf(sfr[st][reg], 0.125f, (&mb.x)[reg]);
    }
    if (CAUSAL && kt == qt) {
      #pragma unroll
      for (int st = 0; st < 4; ++st)
        #pragma unroll
        for (int reg = 0; reg < 4; ++reg)
          if (st * 16 + g * 4 + reg > w * 16 + r) sc[st][reg] = -1e30f;
    }

    // ---- online softmax for row r ----
    float tm = sc[0][0];
    #pragma unroll
    for (int st = 0; st < 4; ++st)
      #pragma unroll
      for (int reg = 0; reg < 4; ++reg) tm = fmaxf(tm, sc[st][reg]);
    tm = fmaxf(tm, __shfl_xor(tm, 16));
    tm = fmaxf(tm, __shfl_xor(tm, 32));
    float mnew  = fmaxf(m, tm);
    float alpha = __expf(m - mnew);
    float pe[4][4], psum = 0.f;
    #pragma unroll
    for (int st = 0; st < 4; ++st)
      #pragma unroll
      for (int reg = 0; reg < 4; ++reg) {
        pe[st][reg] = __expf(sc[st][reg] - mnew);
        psum += pe[st][reg];
      }
    psum += __shfl_xor(psum, 16);
    psum += __shfl_xor(psum, 32);
    lsum = lsum * alpha + psum;
    m = mnew;
    #pragma unroll
    for (int st = 0; st < 4; ++st) {
      short4v ps;
      #pragma unroll
      for (int reg = 0; reg < 4; ++reg) ps[reg] = f2bf(pe[st][reg]);
      *(short4v*)&Pl[w][r][st * 16 + g * 4] = ps;
    }

    // ---- rescale acc (rows q = g*4+reg need alpha from lane q) ----
    float af[4];
    #pragma unroll
    for (int reg = 0; reg < 4; ++reg) af[reg] = __shfl(alpha, g * 4 + reg);
    #pragma unroll
    for (int dt = 0; dt < 4; ++dt)
      #pragma unroll
      for (int reg = 0; reg < 4; ++reg) acc[dt][reg] *= af[reg];

    // ---- PV ----
    #pragma unroll
    for (int kh = 0; kh < 2; ++kh) {
      bf16x8 pf = *(bf16x8*)&Pl[w][r][kh * 32 + g * 8];
      #pragma unroll
      for (int dt = 0; dt < 4; ++dt) {
        bf16x8 vf = *(bf16x8*)&Vt[dt * 16 + r][kh * 32 + g * 8];
        acc[dt] = __builtin_amdgcn_mfma_f32_16x16x32_bf16(pf, vf, acc[dt], 0, 0, 0);
      }
    }
  }

  float inv = (lsum > 0.f) ? (1.f / lsum) : 0.f;
  float invf[4];
  #pragma unroll
  for (int reg = 0; reg < 4; ++reg) invf[reg] = __shfl(inv, g * 4 + reg);
  #pragma unroll
  for (int reg = 0; reg < 4; ++reg) {
    short* orow = O + ((size_t)(b * T + q0 + g * 4 + reg)) * D_ + h * DH_;
    #pragma unroll
    for (int dt = 0; dt < 4; ++dt)
      orow[dt * 16 + r] = f2bf(acc[dt][reg] * invf[reg]);
  }
}

// ---------------------------------------------------------------------------
// out[row] = R[row] + LayerNorm(F[row]) * g + b   (row length 256)
// ---------------------------------------------------------------------------
__global__ __launch_bounds__(256) void ln_res_f32(const float* __restrict__ F,
                                                  const float* __restrict__ R,
                                                  const float* __restrict__ g,
                                                  const float* __restrict__ bt,
                                                  float* __restrict__ out) {
  const int lane = threadIdx.x & 63;
  const int wid  = threadIdx.x >> 6;
  const size_t row  = (size_t)blockIdx.x * 4 + wid;
  const size_t base = row * 256 + (size_t)lane * 4;
  float4 v = *(const float4*)&F[base];
  float s = v.x + v.y + v.z + v.w;
  #pragma unroll
  for (int o = 32; o >= 1; o >>= 1) s += __shfl_xor(s, o);
  float mu = s * (1.f / 256.f);
  float dx = v.x - mu, dy = v.y - mu, dz = v.z - mu, dw = v.w - mu;
  float vr = dx * dx + dy * dy + dz * dz + dw * dw;
  #pragma unroll
  for (int o = 32; o >= 1; o >>= 1) vr += __shfl_xor(vr, o);
  float rstd = rsqrtf(vr * (1.f / 256.f) + 1e-5f);
  float4 g4 = *(const float4*)&g[lane * 4];
  float4 b4 = *(const float4*)&bt[lane * 4];
  float4 r4 = *(const float4*)&R[base];
  float4 o4;
  o4.x = fmaf(dx * rstd, g4.x, b4.x) + r4.x;
  o4.y = fmaf(dy * rstd, g4.y, b4.y) + r4.y;
  o4.z = fmaf(dz * rstd, g4.z, b4.z) + r4.z;
  o4.w = fmaf(dw * rstd, g4.w, b4.w) + r4.w;
  *(float4*)&out[base] = o4;
}

extern "C" void kernel_launch(void* const* d_in, const int* in_sizes, int n_in,
                              void* d_out, int out_size, void* d_ws, size_t ws_size,
                              hipStream_t stream) {
  const float* Xt    = (const float*)d_in[0];
  const float* oMask = (const float*)d_in[1];
  const float* Xe    = (const float*)d_in[2];
  const float* iMask = (const float*)d_in[3];
  const float* Wq1   = (const float*)d_in[4];
  const float* Wk1   = (const float*)d_in[5];
  const float* Wv1   = (const float*)d_in[6];
  const float* Wo1   = (const float*)d_in[7];
  const float* Wq2   = (const float*)d_in[8];
  const float* Wk2   = (const float*)d_in[9];
  const float* Wv2   = (const float*)d_in[10];
  const float* Wo2   = (const float*)d_in[11];
  const float* W1    = (const float*)d_in[12];
  const float* W2    = (const float*)d_in[13];
  const float* g1    = (const float*)d_in[14];
  const float* b1    = (const float*)d_in[15];
  const float* g2    = (const float*)d_in[16];
  const float* b2    = (const float*)d_in[17];
  const float* g3    = (const float*)d_in[18];
  const float* b3    = (const float*)d_in[19];

  const int B = 16, T = 1024, S = 1024;
  const int NT = B * T;
  const size_t SZ = (size_t)NT * 256;   // elems per [NT,256] slot (fp32-sized)

  float* ws = (float*)d_ws;
  float* s0 = ws;
  float* s1 = ws + SZ;
  float* s2 = ws + 2 * SZ;
  float* s3 = ws + 3 * SZ;
  float* s4 = ws + 4 * SZ;
  float* s5 = ws + 5 * SZ;

  dim3 blk(256);
  dim3 gP(NT / 128, 256 / 128);
  dim3 gA(T / 64, B * H_);
  dim3 gF1(NT / 128, 1024 / 128);

  // ---- self-attention block ----
  gemm_mfma<false, true, false, true><<<gP, blk, 0, stream>>>(Xt, Wq1, s0, NT, 256, 256);
  gemm_mfma<false, true, false, true><<<gP, blk, 0, stream>>>(Xt, Wk1, s1, NT, 256, 256);
  gemm_mfma<false, true, false, true><<<gP, blk, 0, stream>>>(Xt, Wv1, s2, NT, 256, 256);
  attn_mfma<true><<<gA, blk, 0, stream>>>((const short*)s0, (const short*)s1, (const short*)s2,
                                          oMask, (short*)s3, T, T);
  gemm_mfma<true, true, false, false><<<gP, blk, 0, stream>>>(s3, Wo1, s0, NT, 256, 256);
  ln_res_f32<<<NT / 4, blk, 0, stream>>>(s0, Xt, g1, b1, s4);

  // ---- cross-attention block ----
  gemm_mfma<false, true, false, true><<<gP, blk, 0, stream>>>(s4, Wq2, s0, NT, 256, 256);
  gemm_mfma<false, true, false, true><<<gP, blk, 0, stream>>>(Xe, Wk2, s1, NT, 256, 256);
  gemm_mfma<false, true, false, true><<<gP, blk, 0, stream>>>(Xe, Wv2, s2, NT, 256, 256);
  attn_mfma<false><<<gA, blk, 0, stream>>>((const short*)s0, (const short*)s1, (const short*)s2,
                                           iMask, (short*)s3, T, S);
  gemm_mfma<true, false, false, false><<<gP, blk, 0, stream>>>(s3, Wo2, s0, NT, 256, 256);
  ln_res_f32<<<NT / 4, blk, 0, stream>>>(s0, s4, g2, b2, s5);

  // ---- FFN ----  (H bf16 spans s0..s1)
  gemm_mfma<false, true, true, true><<<gF1, blk, 0, stream>>>(s5, W1, s0, NT, 256, 1024);
  gemm_mfma<true, true, true, false><<<gP, blk, 0, stream>>>(s0, W2, s4, NT, 1024, 256);
  ln_res_f32<<<NT / 4, blk, 0, stream>>>(s4, s5, g3, b3, (float*)d_out);
}

// Round 5
// 280.255 us; speedup vs baseline: 7.1969x; 1.2156x over previous
//
#include <hip/hip_runtime.h>
#include <math.h>

#define D_ 256
#define H_ 4
#define DH_ 64

typedef __attribute__((ext_vector_type(8))) short bf16x8;
typedef __attribute__((ext_vector_type(4))) short short4v;
typedef __attribute__((ext_vector_type(4))) float f32x4;

__device__ __forceinline__ short f2bf(float x) {
  union { float f; unsigned u; } c; c.f = x;
  unsigned r = (c.u + 0x7fffu + ((c.u >> 16) & 1u)) >> 16;
  return (short)r;
}

// ---------------------------------------------------------------------------
// MFMA GEMM, double-buffered LDS, optional 3-way fused launch (blockIdx.z
// picks A/B/C). C[N,M] = A[N,K] * (TRANSB ? B^T : B), optional ReLU.
// 128x128 tile, BK=64, 4 waves 2x2, 4x4 frags of mfma_f32_16x16x32_bf16.
// Pipeline: prefetch k+1 tile to regs -> compute k from LDS[cur] -> write regs
// to LDS[cur^1] -> one barrier per k-step.
// ---------------------------------------------------------------------------
template<bool ABF16, bool TRANSB, bool RELU, bool CBF16>
__global__ __launch_bounds__(256) void gemm_mfma(
    const void* __restrict__ A0, const void* __restrict__ A1, const void* __restrict__ A2,
    const float* __restrict__ B0, const float* __restrict__ B1, const float* __restrict__ B2,
    void* __restrict__ C0, void* __restrict__ C1, void* __restrict__ C2,
    int N, int K, int M) {
  __shared__ short Al[2][128][72];
  __shared__ short Bl[2][128][72];
  const int tid = threadIdx.x;
  const int w   = tid >> 6;
  const int l   = tid & 63;
  const int bn  = blockIdx.x * 128;
  const int bm  = blockIdx.y * 128;
  const int z   = blockIdx.z;
  const void*  Av = (z == 0) ? A0 : ((z == 1) ? A1 : A2);
  const float* B  = (z == 0) ? B0 : ((z == 1) ? B1 : B2);
  void*        Cv = (z == 0) ? C0 : ((z == 1) ? C1 : C2);
  const int wm = (w >> 1) * 64;
  const int wn = (w & 1) * 64;
  const int fr = l & 15;
  const int fg = l >> 4;

  f32x4 acc[4][4];
  #pragma unroll
  for (int mi = 0; mi < 4; ++mi)
    #pragma unroll
    for (int ni = 0; ni < 4; ++ni) acc[mi][ni] = (f32x4){0.f, 0.f, 0.f, 0.f};

  const int sr = tid >> 1;
  const int sc = (tid & 1) * 32;

  float4 arf[8]; bf16x8 arb[4]; float4 brf[8];

  auto loadA = [&](int k0) {
    if (ABF16) {
      const short* arow = (const short*)Av + (size_t)(bn + sr) * K + k0 + sc;
      #pragma unroll
      for (int i = 0; i < 4; ++i) arb[i] = *(const bf16x8*)&arow[i * 8];
    } else {
      const float* arow = (const float*)Av + (size_t)(bn + sr) * K + k0 + sc;
      #pragma unroll
      for (int i = 0; i < 8; ++i) arf[i] = *(const float4*)&arow[i * 4];
    }
  };
  auto loadB = [&](int k0) {
    if (TRANSB) {
      const float* brow = B + (size_t)(bm + sr) * K + k0 + sc;
      #pragma unroll
      for (int i = 0; i < 8; ++i) brf[i] = *(const float4*)&brow[i * 4];
    } else {
      #pragma unroll
      for (int i = 0; i < 8; ++i) {
        int idx = tid + i * 256;
        int kk = idx >> 5;
        int c4 = (idx & 31) * 4;
        brf[i] = *(const float4*)&B[(size_t)(k0 + kk) * M + bm + c4];
      }
    }
  };
  auto store = [&](int buf) {
    if (ABF16) {
      #pragma unroll
      for (int i = 0; i < 4; ++i) *(bf16x8*)&Al[buf][sr][sc + i * 8] = arb[i];
    } else {
      #pragma unroll
      for (int i = 0; i < 8; ++i) {
        float4 v = arf[i];
        short4v s; s[0] = f2bf(v.x); s[1] = f2bf(v.y); s[2] = f2bf(v.z); s[3] = f2bf(v.w);
        *(short4v*)&Al[buf][sr][sc + i * 4] = s;
      }
    }
    if (TRANSB) {
      #pragma unroll
      for (int i = 0; i < 8; ++i) {
        float4 v = brf[i];
        short4v s; s[0] = f2bf(v.x); s[1] = f2bf(v.y); s[2] = f2bf(v.z); s[3] = f2bf(v.w);
        *(short4v*)&Bl[buf][sr][sc + i * 4] = s;
      }
    } else {
      #pragma unroll
      for (int i = 0; i < 8; ++i) {
        int idx = tid + i * 256;
        int kk = idx >> 5;
        int c4 = (idx & 31) * 4;
        float4 v = brf[i];
        Bl[buf][c4 + 0][kk] = f2bf(v.x);
        Bl[buf][c4 + 1][kk] = f2bf(v.y);
        Bl[buf][c4 + 2][kk] = f2bf(v.z);
        Bl[buf][c4 + 3][kk] = f2bf(v.w);
      }
    }
  };

  loadA(0); loadB(0); store(0);
  __syncthreads();
  const int nk = K >> 6;
  for (int s = 0; s < nk; ++s) {
    const int cur = s & 1;
    if (s + 1 < nk) { loadA((s + 1) << 6); loadB((s + 1) << 6); }
    #pragma unroll
    for (int kh = 0; kh < 2; ++kh) {
      bf16x8 af[4], bfr[4];
      #pragma unroll
      for (int mi = 0; mi < 4; ++mi)
        af[mi] = *(bf16x8*)&Al[cur][wm + mi * 16 + fr][kh * 32 + fg * 8];
      #pragma unroll
      for (int ni = 0; ni < 4; ++ni)
        bfr[ni] = *(bf16x8*)&Bl[cur][wn + ni * 16 + fr][kh * 32 + fg * 8];
      #pragma unroll
      for (int mi = 0; mi < 4; ++mi)
        #pragma unroll
        for (int ni = 0; ni < 4; ++ni)
          acc[mi][ni] = __builtin_amdgcn_mfma_f32_16x16x32_bf16(af[mi], bfr[ni], acc[mi][ni], 0, 0, 0);
    }
    if (s + 1 < nk) store(cur ^ 1);
    __syncthreads();
  }

  #pragma unroll
  for (int mi = 0; mi < 4; ++mi) {
    #pragma unroll
    for (int reg = 0; reg < 4; ++reg) {
      size_t rowbase = (size_t)(bn + wm + mi * 16 + fg * 4 + reg) * M + bm + wn;
      #pragma unroll
      for (int ni = 0; ni < 4; ++ni) {
        float v = acc[mi][ni][reg];
        if (RELU) v = fmaxf(v, 0.f);
        if (CBF16) ((short*)Cv)[rowbase + ni * 16 + fr] = f2bf(v);
        else       ((float*)Cv)[rowbase + ni * 16 + fr] = v;
      }
    }
  }
}

// ---------------------------------------------------------------------------
// bf16 MFMA flash attention, swapped-QK^T softmax, defer-max (thr=8).
// CAUSAL: grid.x = T/128; block processes strips {bx, (T/64-1)-bx} -> every
// block walks exactly T/64+1 K-tiles (load-balanced). Non-causal: one strip.
// ---------------------------------------------------------------------------
template<bool CAUSAL>
__global__ __launch_bounds__(256) void attn_mfma(const short* __restrict__ Q,
                                                 const short* __restrict__ Kg,
                                                 const short* __restrict__ Vg,
                                                 const float* __restrict__ mask,
                                                 short* __restrict__ O,
                                                 int T, int Lk) {
  __shared__ short Kl[64][72];
  __shared__ short Vt[64][72];
  __shared__ short Pl[4][16][72];
  __shared__ float Mb[64];
  const int tid = threadIdx.x;
  const int l   = tid & 63;
  const int w   = tid >> 6;
  const int b   = blockIdx.y >> 2;
  const int h   = blockIdx.y & 3;
  const int r   = l & 15;
  const int g   = l >> 4;

  const short* Kbase = Kg + (size_t)b * Lk * D_ + h * DH_;
  const short* Vbase = Vg + (size_t)b * Lk * D_ + h * DH_;
  const float* mrow  = mask + (size_t)b * Lk;

  const int kr = tid >> 2, kq = (tid & 3) * 16;
  const int bi = tid & 15, bj = tid >> 4;

  const int nsp = CAUSAL ? 2 : 1;
  for (int sp = 0; sp < nsp; ++sp) {
    const int qt = CAUSAL ? (sp == 0 ? (int)blockIdx.x : (T >> 6) - 1 - (int)blockIdx.x)
                          : (int)blockIdx.x;
    const int q0 = qt * 64 + w * 16;

    bf16x8 qf[2];
    {
      const short* qrow = Q + ((size_t)(b * T + q0 + r)) * D_ + h * DH_;
      qf[0] = *(const bf16x8*)&qrow[g * 8];
      qf[1] = *(const bf16x8*)&qrow[32 + g * 8];
    }

    float m = -1e30f, lsum = 0.f;
    f32x4 acc[4];
    #pragma unroll
    for (int dt = 0; dt < 4; ++dt) acc[dt] = (f32x4){0.f, 0.f, 0.f, 0.f};

    const int nkt = CAUSAL ? (qt + 1) : (Lk / 64);
    for (int kt = 0; kt < nkt; ++kt) {
      __syncthreads();
      if (tid < 64) {
        float v = mrow[kt * 64 + tid];
        Mb[tid] = (v != 0.f) ? 0.f : -1e30f;
      }
      {  // K: direct bf16 copy
        const short* kgr = Kbase + (size_t)(kt * 64 + kr) * D_ + kq;
        *(bf16x8*)&Kl[kr][kq]     = *(const bf16x8*)&kgr[0];
        *(bf16x8*)&Kl[kr][kq + 8] = *(const bf16x8*)&kgr[8];
      }
      {  // V: 4x4 in-reg transpose
        short4v vv[4];
        #pragma unroll
        for (int i = 0; i < 4; ++i)
          vv[i] = *(const short4v*)&Vbase[(size_t)(kt * 64 + bj * 4 + i) * D_ + bi * 4];
        #pragma unroll
        for (int j = 0; j < 4; ++j) {
          short4v s; s[0] = vv[0][j]; s[1] = vv[1][j]; s[2] = vv[2][j]; s[3] = vv[3][j];
          *(short4v*)&Vt[bi * 4 + j][bj * 4] = s;
        }
      }
      __syncthreads();

      // ---- swapped QK^T: lane owns q-row r; k = st*16 + g*4 + reg ----
      f32x4 sfr[4];
      #pragma unroll
      for (int st = 0; st < 4; ++st) {
        sfr[st] = (f32x4){0.f, 0.f, 0.f, 0.f};
        #pragma unroll
        for (int kh = 0; kh < 2; ++kh) {
          bf16x8 kf = *(bf16x8*)&Kl[st * 16 + r][kh * 32 + g * 8];
          sfr[st] = __builtin_amdgcn_mfma_f32_16x16x32_bf16(kf, qf[kh], sfr[st], 0, 0, 0);
        }
      }

      float sc[4][4];
      #pragma unroll
      for (int st = 0; st < 4; ++st) {
        float4 mb = *(float4*)&Mb[st * 16 + g * 4];
        #pragma unroll
        for (int reg = 0; reg < 4; ++reg)
          sc[st][reg] = fmaf(sfr[st][reg], 0.125f, (&mb.x)[reg]);
      }
      if (CAUSAL && kt == qt) {
        #pragma unroll
        for (int st = 0; st < 4; ++st)
          #pragma unroll
          for (int reg = 0; reg < 4; ++reg)
            if (st * 16 + g * 4 + reg > w * 16 + r) sc[st][reg] = -1e30f;
      }

      // ---- online softmax with defer-max (thr=8) ----
      float tm = sc[0][0];
      #pragma unroll
      for (int st = 0; st < 4; ++st)
        #pragma unroll
        for (int reg = 0; reg < 4; ++reg) tm = fmaxf(tm, sc[st][reg]);
      tm = fmaxf(tm, __shfl_xor(tm, 16));
      tm = fmaxf(tm, __shfl_xor(tm, 32));
      const int need = __any(tm - m > 8.f);
      float mnew = need ? fmaxf(m, tm) : m;
      float pe[4][4], psum = 0.f;
      #pragma unroll
      for (int st = 0; st < 4; ++st)
        #pragma unroll
        for (int reg = 0; reg < 4; ++reg) {
          pe[st][reg] = __expf(sc[st][reg] - mnew);
          psum += pe[st][reg];
        }
      psum += __shfl_xor(psum, 16);
      psum += __shfl_xor(psum, 32);
      #pragma unroll
      for (int st = 0; st < 4; ++st) {
        short4v ps;
        #pragma unroll
        for (int reg = 0; reg < 4; ++reg) ps[reg] = f2bf(pe[st][reg]);
        *(short4v*)&Pl[w][r][st * 16 + g * 4] = ps;
      }
      if (need) {
        float alpha = __expf(m - mnew);
        lsum = lsum * alpha + psum;
        m = mnew;
        float af[4];
        #pragma unroll
        for (int reg = 0; reg < 4; ++reg) af[reg] = __shfl(alpha, g * 4 + reg);
        #pragma unroll
        for (int dt = 0; dt < 4; ++dt)
          #pragma unroll
          for (int reg = 0; reg < 4; ++reg) acc[dt][reg] *= af[reg];
      } else {
        lsum += psum;
      }

      // ---- PV ----
      #pragma unroll
      for (int kh = 0; kh < 2; ++kh) {
        bf16x8 pf = *(bf16x8*)&Pl[w][r][kh * 32 + g * 8];
        #pragma unroll
        for (int dt = 0; dt < 4; ++dt) {
          bf16x8 vf = *(bf16x8*)&Vt[dt * 16 + r][kh * 32 + g * 8];
          acc[dt] = __builtin_amdgcn_mfma_f32_16x16x32_bf16(pf, vf, acc[dt], 0, 0, 0);
        }
      }
    }

    float inv = (lsum > 0.f) ? (1.f / lsum) : 0.f;
    float invf[4];
    #pragma unroll
    for (int reg = 0; reg < 4; ++reg) invf[reg] = __shfl(inv, g * 4 + reg);
    #pragma unroll
    for (int reg = 0; reg < 4; ++reg) {
      short* orow = O + ((size_t)(b * T + q0 + g * 4 + reg)) * D_ + h * DH_;
      #pragma unroll
      for (int dt = 0; dt < 4; ++dt)
        orow[dt * 16 + r] = f2bf(acc[dt][reg] * invf[reg]);
    }
  }
}

// ---------------------------------------------------------------------------
// out[row] = R[row] + LayerNorm(F[row]) * g + b   (row length 256)
// ---------------------------------------------------------------------------
__global__ __launch_bounds__(256) void ln_res_f32(const float* __restrict__ F,
                                                  const float* __restrict__ R,
                                                  const float* __restrict__ g,
                                                  const float* __restrict__ bt,
                                                  float* __restrict__ out) {
  const int lane = threadIdx.x & 63;
  const int wid  = threadIdx.x >> 6;
  const size_t row  = (size_t)blockIdx.x * 4 + wid;
  const size_t base = row * 256 + (size_t)lane * 4;
  float4 v = *(const float4*)&F[base];
  float s = v.x + v.y + v.z + v.w;
  #pragma unroll
  for (int o = 32; o >= 1; o >>= 1) s += __shfl_xor(s, o);
  float mu = s * (1.f / 256.f);
  float dx = v.x - mu, dy = v.y - mu, dz = v.z - mu, dw = v.w - mu;
  float vr = dx * dx + dy * dy + dz * dz + dw * dw;
  #pragma unroll
  for (int o = 32; o >= 1; o >>= 1) vr += __shfl_xor(vr, o);
  float rstd = rsqrtf(vr * (1.f / 256.f) + 1e-5f);
  float4 g4 = *(const float4*)&g[lane * 4];
  float4 b4 = *(const float4*)&bt[lane * 4];
  float4 r4 = *(const float4*)&R[base];
  float4 o4;
  o4.x = fmaf(dx * rstd, g4.x, b4.x) + r4.x;
  o4.y = fmaf(dy * rstd, g4.y, b4.y) + r4.y;
  o4.z = fmaf(dz * rstd, g4.z, b4.z) + r4.z;
  o4.w = fmaf(dw * rstd, g4.w, b4.w) + r4.w;
  *(float4*)&out[base] = o4;
}

extern "C" void kernel_launch(void* const* d_in, const int* in_sizes, int n_in,
                              void* d_out, int out_size, void* d_ws, size_t ws_size,
                              hipStream_t stream) {
  const float* Xt    = (const float*)d_in[0];
  const float* oMask = (const float*)d_in[1];
  const float* Xe    = (const float*)d_in[2];
  const float* iMask = (const float*)d_in[3];
  const float* Wq1   = (const float*)d_in[4];
  const float* Wk1   = (const float*)d_in[5];
  const float* Wv1   = (const float*)d_in[6];
  const float* Wo1   = (const float*)d_in[7];
  const float* Wq2   = (const float*)d_in[8];
  const float* Wk2   = (const float*)d_in[9];
  const float* Wv2   = (const float*)d_in[10];
  const float* Wo2   = (const float*)d_in[11];
  const float* W1    = (const float*)d_in[12];
  const float* W2    = (const float*)d_in[13];
  const float* g1    = (const float*)d_in[14];
  const float* b1    = (const float*)d_in[15];
  const float* g2    = (const float*)d_in[16];
  const float* b2    = (const float*)d_in[17];
  const float* g3    = (const float*)d_in[18];
  const float* b3    = (const float*)d_in[19];

  const int B = 16, T = 1024, S = 1024;
  const int NT = B * T;
  const size_t SZ = (size_t)NT * 256;

  float* ws = (float*)d_ws;
  float* s0 = ws;
  float* s1 = ws + SZ;
  float* s2 = ws + 2 * SZ;
  float* s3 = ws + 3 * SZ;
  float* s4 = ws + 4 * SZ;
  float* s5 = ws + 5 * SZ;

  dim3 blk(256);
  dim3 gQKV(NT / 128, 2, 3);
  dim3 gP1(NT / 128, 2, 1);
  dim3 gF1(NT / 128, 8, 1);
  dim3 gAs(T / 128, B * H_);   // paired causal strips
  dim3 gAc(T / 64, B * H_);

  // ---- self-attention block ----
  gemm_mfma<false, true, false, true><<<gQKV, blk, 0, stream>>>(
      Xt, Xt, Xt, Wq1, Wk1, Wv1, s0, s1, s2, NT, 256, 256);
  attn_mfma<true><<<gAs, blk, 0, stream>>>((const short*)s0, (const short*)s1, (const short*)s2,
                                           oMask, (short*)s3, T, T);
  gemm_mfma<true, true, false, false><<<gP1, blk, 0, stream>>>(
      s3, s3, s3, Wo1, Wo1, Wo1, s0, s0, s0, NT, 256, 256);
  ln_res_f32<<<NT / 4, blk, 0, stream>>>(s0, Xt, g1, b1, s4);

  // ---- cross-attention block ----
  gemm_mfma<false, true, false, true><<<gQKV, blk, 0, stream>>>(
      s4, Xe, Xe, Wq2, Wk2, Wv2, s0, s1, s2, NT, 256, 256);
  attn_mfma<false><<<gAc, blk, 0, stream>>>((const short*)s0, (const short*)s1, (const short*)s2,
                                            iMask, (short*)s3, T, S);
  gemm_mfma<true, false, false, false><<<gP1, blk, 0, stream>>>(
      s3, s3, s3, Wo2, Wo2, Wo2, s0, s0, s0, NT, 256, 256);
  ln_res_f32<<<NT / 4, blk, 0, stream>>>(s0, s4, g2, b2, s5);

  // ---- FFN ----
  gemm_mfma<false, true, true, true><<<gF1, blk, 0, stream>>>(
      s5, s5, s5, W1, W1, W1, s0, s0, s0, NT, 256, 1024);
  gemm_mfma<true, true, true, false><<<gP1, blk, 0, stream>>>(
      s0, s0, s0, W2, W2, W2, s4, s4, s4, NT, 1024, 256);
  ln_res_f32<<<NT / 4, blk, 0, stream>>>(s4, s5, g3, b3, (float*)d_out);
}

// Round 6
// 262.548 us; speedup vs baseline: 7.6822x; 1.0674x over previous
//
#include <hip/hip_runtime.h>
#include <math.h>

#define D_ 256
#define H_ 4
#define DH_ 64
#define NKT_ 16          // K/V tiles per (b,h): 1024/64
#define TPB_BITS 10      // tokens per batch = 1024

typedef __attribute__((ext_vector_type(8))) short bf16x8;
typedef __attribute__((ext_vector_type(4))) short short4v;
typedef __attribute__((ext_vector_type(4))) float f32x4;

__device__ __forceinline__ short f2bf(float x) {
  union { float f; unsigned u; } c; c.f = x;
  unsigned r = (c.u + 0x7fffu + ((c.u >> 16) & 1u)) >> 16;
  return (short)r;
}
__device__ __forceinline__ float bf2f(short s) {
  union { unsigned u; float f; } c; c.u = ((unsigned)(unsigned short)s) << 16;
  return c.f;
}
__device__ __forceinline__ unsigned cvtpk(float lo, float hi) {
  unsigned r;
  asm("v_cvt_pk_bf16_f32 %0, %1, %2" : "=v"(r) : "v"(lo), "v"(hi));
  return r;
}
#if __has_builtin(__builtin_amdgcn_exp2f)
#define EXP2F(x) __builtin_amdgcn_exp2f(x)
#else
#define EXP2F(x) __expf(0.6931471805599453f * (x))
#endif

// ---------------------------------------------------------------------------
// MFMA GEMM, double-buffered LDS, optional fused multi-op launch (blockIdx.z
// picks A/B/C). C[N,M] = A[N,K] * (TRANSB ? B^T : B), optional ReLU.
// If z == vtrans_z, C is written tiled-transposed [b][h][kt][64d][64k] bf16
// (V for attention). 128x128 tile, BK=64, 4 waves 2x2.
// ---------------------------------------------------------------------------
template<bool ABF16, bool TRANSB, bool RELU, bool CBF16>
__global__ __launch_bounds__(256) void gemm_mfma(
    const void* __restrict__ A0, const void* __restrict__ A1, const void* __restrict__ A2,
    const float* __restrict__ B0, const float* __restrict__ B1, const float* __restrict__ B2,
    void* __restrict__ C0, void* __restrict__ C1, void* __restrict__ C2,
    int N, int K, int M, int vtrans_z) {
  __shared__ short Al[2][128][72];
  __shared__ short Bl[2][128][72];
  const int tid = threadIdx.x;
  const int w   = tid >> 6;
  const int l   = tid & 63;
  const int bn  = blockIdx.x * 128;
  const int bm  = blockIdx.y * 128;
  const int z   = blockIdx.z;
  const void*  Av = (z == 0) ? A0 : ((z == 1) ? A1 : A2);
  const float* B  = (z == 0) ? B0 : ((z == 1) ? B1 : B2);
  void*        Cv = (z == 0) ? C0 : ((z == 1) ? C1 : C2);
  const int wm = (w >> 1) * 64;
  const int wn = (w & 1) * 64;
  const int fr = l & 15;
  const int fg = l >> 4;

  f32x4 acc[4][4];
  #pragma unroll
  for (int mi = 0; mi < 4; ++mi)
    #pragma unroll
    for (int ni = 0; ni < 4; ++ni) acc[mi][ni] = (f32x4){0.f, 0.f, 0.f, 0.f};

  const int sr = tid >> 1;
  const int sc = (tid & 1) * 32;

  float4 arf[8]; bf16x8 arb[4]; float4 brf[8];

  auto loadA = [&](int k0) {
    if (ABF16) {
      const short* arow = (const short*)Av + (size_t)(bn + sr) * K + k0 + sc;
      #pragma unroll
      for (int i = 0; i < 4; ++i) arb[i] = *(const bf16x8*)&arow[i * 8];
    } else {
      const float* arow = (const float*)Av + (size_t)(bn + sr) * K + k0 + sc;
      #pragma unroll
      for (int i = 0; i < 8; ++i) arf[i] = *(const float4*)&arow[i * 4];
    }
  };
  auto loadB = [&](int k0) {
    if (TRANSB) {
      const float* brow = B + (size_t)(bm + sr) * K + k0 + sc;
      #pragma unroll
      for (int i = 0; i < 8; ++i) brf[i] = *(const float4*)&brow[i * 4];
    } else {
      #pragma unroll
      for (int i = 0; i < 8; ++i) {
        int idx = tid + i * 256;
        int kk = idx >> 5;
        int c4 = (idx & 31) * 4;
        brf[i] = *(const float4*)&B[(size_t)(k0 + kk) * M + bm + c4];
      }
    }
  };
  auto store = [&](int buf) {
    if (ABF16) {
      #pragma unroll
      for (int i = 0; i < 4; ++i) *(bf16x8*)&Al[buf][sr][sc + i * 8] = arb[i];
    } else {
      #pragma unroll
      for (int i = 0; i < 8; ++i) {
        float4 v = arf[i];
        short4v s; s[0] = f2bf(v.x); s[1] = f2bf(v.y); s[2] = f2bf(v.z); s[3] = f2bf(v.w);
        *(short4v*)&Al[buf][sr][sc + i * 4] = s;
      }
    }
    if (TRANSB) {
      #pragma unroll
      for (int i = 0; i < 8; ++i) {
        float4 v = brf[i];
        short4v s; s[0] = f2bf(v.x); s[1] = f2bf(v.y); s[2] = f2bf(v.z); s[3] = f2bf(v.w);
        *(short4v*)&Bl[buf][sr][sc + i * 4] = s;
      }
    } else {
      #pragma unroll
      for (int i = 0; i < 8; ++i) {
        int idx = tid + i * 256;
        int kk = idx >> 5;
        int c4 = (idx & 31) * 4;
        float4 v = brf[i];
        Bl[buf][c4 + 0][kk] = f2bf(v.x);
        Bl[buf][c4 + 1][kk] = f2bf(v.y);
        Bl[buf][c4 + 2][kk] = f2bf(v.z);
        Bl[buf][c4 + 3][kk] = f2bf(v.w);
      }
    }
  };

  loadA(0); loadB(0); store(0);
  __syncthreads();
  const int nk = K >> 6;
  for (int s = 0; s < nk; ++s) {
    const int cur = s & 1;
    if (s + 1 < nk) { loadA((s + 1) << 6); loadB((s + 1) << 6); }
    #pragma unroll
    for (int kh = 0; kh < 2; ++kh) {
      bf16x8 af[4], bfr[4];
      #pragma unroll
      for (int mi = 0; mi < 4; ++mi)
        af[mi] = *(bf16x8*)&Al[cur][wm + mi * 16 + fr][kh * 32 + fg * 8];
      #pragma unroll
      for (int ni = 0; ni < 4; ++ni)
        bfr[ni] = *(bf16x8*)&Bl[cur][wn + ni * 16 + fr][kh * 32 + fg * 8];
      #pragma unroll
      for (int mi = 0; mi < 4; ++mi)
        #pragma unroll
        for (int ni = 0; ni < 4; ++ni)
          acc[mi][ni] = __builtin_amdgcn_mfma_f32_16x16x32_bf16(af[mi], bfr[ni], acc[mi][ni], 0, 0, 0);
    }
    if (s + 1 < nk) store(cur ^ 1);
    __syncthreads();
  }

  if (z == vtrans_z) {
    // tiled-transposed V^T write: [b][h][kt][d=64][k=64] bf16
    #pragma unroll
    for (int mi = 0; mi < 4; ++mi) {
      int nbase = bn + wm + mi * 16 + fg * 4;     // token index of reg 0
      int b_  = nbase >> TPB_BITS;
      int key = nbase & ((1 << TPB_BITS) - 1);
      int kt  = key >> 6, kin = key & 63;
      #pragma unroll
      for (int ni = 0; ni < 4; ++ni) {
        int col = bm + wn + ni * 16 + fr;
        int h_ = col >> 6, dh = col & 63;
        short4v s;
        #pragma unroll
        for (int reg = 0; reg < 4; ++reg) s[reg] = f2bf(acc[mi][ni][reg]);
        *(short4v*)&((short*)Cv)[((((size_t)(b_ * H_ + h_) * NKT_) + kt) << 12) + dh * 64 + kin] = s;
      }
    }
  } else {
    #pragma unroll
    for (int mi = 0; mi < 4; ++mi) {
      #pragma unroll
      for (int reg = 0; reg < 4; ++reg) {
        size_t rowbase = (size_t)(bn + wm + mi * 16 + fg * 4 + reg) * M + bm + wn;
        #pragma unroll
        for (int ni = 0; ni < 4; ++ni) {
          float v = acc[mi][ni][reg];
          if (RELU) v = fmaxf(v, 0.f);
          if (CBF16) ((short*)Cv)[rowbase + ni * 16 + fr] = f2bf(v);
          else       ((float*)Cv)[rowbase + ni * 16 + fr] = v;
        }
      }
    }
  }
}

// ---------------------------------------------------------------------------
// bf16 MFMA flash attention, swapped-QK^T, log2-domain softmax, defer-max.
// V read from pre-transposed [b][h][kt][64d][64k]. No mask LDS; bias in regs.
// CAUSAL: paired strips {bx, last-bx}.
// ---------------------------------------------------------------------------
template<bool CAUSAL>
__global__ __launch_bounds__(256) void attn_mfma(const short* __restrict__ Q,
                                                 const short* __restrict__ Kg,
                                                 const short* __restrict__ VT,
                                                 const float* __restrict__ mask,
                                                 short* __restrict__ O,
                                                 int T, int Lk) {
  __shared__ short Kl[64][72];
  __shared__ short Vt[64][72];
  __shared__ short Pl[4][16][72];
  const int tid = threadIdx.x;
  const int l   = tid & 63;
  const int w   = tid >> 6;
  const int b   = blockIdx.y >> 2;
  const int h   = blockIdx.y & 3;
  const int r   = l & 15;
  const int g   = l >> 4;
  const float SCL2E = 0.125f * 1.4426950408889634f;  // scale * log2(e)

  const short* Kbase  = Kg + (size_t)b * Lk * D_ + h * DH_;
  const short* VTbase = VT + (((size_t)(b * H_ + h) * (Lk >> 6)) << 12);
  const float* mrow   = mask + (size_t)b * Lk;

  const int kr = tid >> 2, kq = (tid & 3) * 16;

  const int nsp = CAUSAL ? 2 : 1;
  for (int sp = 0; sp < nsp; ++sp) {
    const int qt = CAUSAL ? (sp == 0 ? (int)blockIdx.x : (T >> 6) - 1 - (int)blockIdx.x)
                          : (int)blockIdx.x;
    const int q0 = qt * 64 + w * 16;

    bf16x8 qf[2];
    {
      const short* qrow = Q + ((size_t)(b * T + q0 + r)) * D_ + h * DH_;
      qf[0] = *(const bf16x8*)&qrow[g * 8];
      qf[1] = *(const bf16x8*)&qrow[32 + g * 8];
    }

    float m = -1e30f, lsum = 0.f;
    f32x4 acc[4];
    #pragma unroll
    for (int dt = 0; dt < 4; ++dt) acc[dt] = (f32x4){0.f, 0.f, 0.f, 0.f};

    const int nkt = CAUSAL ? (qt + 1) : (Lk / 64);
    for (int kt = 0; kt < nkt; ++kt) {
      __syncthreads();
      {  // K: straight bf16 copy
        const short* kgr = Kbase + (size_t)(kt * 64 + kr) * D_ + kq;
        *(bf16x8*)&Kl[kr][kq]     = *(const bf16x8*)&kgr[0];
        *(bf16x8*)&Kl[kr][kq + 8] = *(const bf16x8*)&kgr[8];
      }
      {  // V^T: straight bf16 copy from pre-transposed tile
        const short* vgr = VTbase + ((size_t)kt << 12) + kr * 64 + kq;
        *(bf16x8*)&Vt[kr][kq]     = *(const bf16x8*)&vgr[0];
        *(bf16x8*)&Vt[kr][kq + 8] = *(const bf16x8*)&vgr[8];
      }
      __syncthreads();

      // ---- swapped QK^T: lane owns q-row r; k = st*16 + g*4 + reg ----
      f32x4 sfr[4];
      #pragma unroll
      for (int st = 0; st < 4; ++st) {
        sfr[st] = (f32x4){0.f, 0.f, 0.f, 0.f};
        #pragma unroll
        for (int kh = 0; kh < 2; ++kh) {
          bf16x8 kf = *(bf16x8*)&Kl[st * 16 + r][kh * 32 + g * 8];
          sfr[st] = __builtin_amdgcn_mfma_f32_16x16x32_bf16(kf, qf[kh], sfr[st], 0, 0, 0);
        }
      }

      // ---- scale to log2 domain + mask bias ----
      float sc[4][4];
      #pragma unroll
      for (int st = 0; st < 4; ++st) {
        float4 mv = *(const float4*)&mrow[kt * 64 + st * 16 + g * 4];
        #pragma unroll
        for (int reg = 0; reg < 4; ++reg) {
          float bias = fmaf((&mv.x)[reg], 1e30f, -1e30f);   // 1 -> 0, 0 -> -1e30
          sc[st][reg] = fmaf(sfr[st][reg], SCL2E, bias);
        }
      }
      if (CAUSAL && kt == qt) {
        #pragma unroll
        for (int st = 0; st < 4; ++st)
          #pragma unroll
          for (int reg = 0; reg < 4; ++reg)
            if (st * 16 + g * 4 + reg > w * 16 + r) sc[st][reg] = -1e30f;
      }

      // ---- online softmax (log2 domain), defer-max thr=8 ----
      float tm = sc[0][0];
      #pragma unroll
      for (int st = 0; st < 4; ++st)
        #pragma unroll
        for (int reg = 0; reg < 4; ++reg) tm = fmaxf(tm, sc[st][reg]);
      tm = fmaxf(tm, __shfl_xor(tm, 16));
      tm = fmaxf(tm, __shfl_xor(tm, 32));
      const int need = __any(tm - m > 8.f);
      float mnew = need ? fmaxf(m, tm) : m;
      float pe[4][4], psum = 0.f;
      #pragma unroll
      for (int st = 0; st < 4; ++st)
        #pragma unroll
        for (int reg = 0; reg < 4; ++reg) {
          pe[st][reg] = EXP2F(sc[st][reg] - mnew);
          psum += pe[st][reg];
        }
      psum += __shfl_xor(psum, 16);
      psum += __shfl_xor(psum, 32);
      #pragma unroll
      for (int st = 0; st < 4; ++st) {
        uint2 u;
        u.x = cvtpk(pe[st][0], pe[st][1]);
        u.y = cvtpk(pe[st][2], pe[st][3]);
        *(uint2*)&Pl[w][r][st * 16 + g * 4] = u;
      }
      if (need) {
        float alpha = EXP2F(m - mnew);
        lsum = lsum * alpha + psum;
        m = mnew;
        float af[4];
        #pragma unroll
        for (int reg = 0; reg < 4; ++reg) af[reg] = __shfl(alpha, g * 4 + reg);
        #pragma unroll
        for (int dt = 0; dt < 4; ++dt)
          #pragma unroll
          for (int reg = 0; reg < 4; ++reg) acc[dt][reg] *= af[reg];
      } else {
        lsum += psum;
      }

      // ---- PV ----
      #pragma unroll
      for (int kh = 0; kh < 2; ++kh) {
        bf16x8 pf = *(bf16x8*)&Pl[w][r][kh * 32 + g * 8];
        #pragma unroll
        for (int dt = 0; dt < 4; ++dt) {
          bf16x8 vf = *(bf16x8*)&Vt[dt * 16 + r][kh * 32 + g * 8];
          acc[dt] = __builtin_amdgcn_mfma_f32_16x16x32_bf16(pf, vf, acc[dt], 0, 0, 0);
        }
      }
    }

    float inv = (lsum > 0.f) ? (1.f / lsum) : 0.f;
    float invf[4];
    #pragma unroll
    for (int reg = 0; reg < 4; ++reg) invf[reg] = __shfl(inv, g * 4 + reg);
    #pragma unroll
    for (int reg = 0; reg < 4; ++reg) {
      short* orow = O + ((size_t)(b * T + q0 + g * 4 + reg)) * D_ + h * DH_;
      #pragma unroll
      for (int dt = 0; dt < 4; ++dt)
        orow[dt * 16 + r] = f2bf(acc[dt][reg] * invf[reg]);
    }
  }
}

// ---------------------------------------------------------------------------
// out[row] = R[row] + LayerNorm(F[row]) * g + b   (row length 256, F bf16)
// ---------------------------------------------------------------------------
template<bool RBF16, bool OBF16>
__global__ __launch_bounds__(256) void ln_res(const short* __restrict__ F,
                                              const void* __restrict__ Rv,
                                              const float* __restrict__ g,
                                              const float* __restrict__ bt,
                                              void* __restrict__ outv) {
  const int lane = threadIdx.x & 63;
  const int wid  = threadIdx.x >> 6;
  const size_t row  = (size_t)blockIdx.x * 4 + wid;
  const size_t base = row * 256 + (size_t)lane * 4;
  short4v fv = *(const short4v*)&F[base];
  float vx = bf2f(fv[0]), vy = bf2f(fv[1]), vz = bf2f(fv[2]), vw = bf2f(fv[3]);
  float s = vx + vy + vz + vw;
  #pragma unroll
  for (int o = 32; o >= 1; o >>= 1) s += __shfl_xor(s, o);
  float mu = s * (1.f / 256.f);
  float dx = vx - mu, dy = vy - mu, dz = vz - mu, dw = vw - mu;
  float vr = dx * dx + dy * dy + dz * dz + dw * dw;
  #pragma unroll
  for (int o = 32; o >= 1; o >>= 1) vr += __shfl_xor(vr, o);
  float rstd = rsqrtf(vr * (1.f / 256.f) + 1e-5f);
  float4 g4 = *(const float4*)&g[lane * 4];
  float4 b4 = *(const float4*)&bt[lane * 4];
  float rx, ry, rz, rw;
  if (RBF16) {
    short4v r4 = *(const short4v*)&((const short*)Rv)[base];
    rx = bf2f(r4[0]); ry = bf2f(r4[1]); rz = bf2f(r4[2]); rw = bf2f(r4[3]);
  } else {
    float4 r4 = *(const float4*)&((const float*)Rv)[base];
    rx = r4.x; ry = r4.y; rz = r4.z; rw = r4.w;
  }
  float ox = fmaf(dx * rstd, g4.x, b4.x) + rx;
  float oy = fmaf(dy * rstd, g4.y, b4.y) + ry;
  float oz = fmaf(dz * rstd, g4.z, b4.z) + rz;
  float ow = fmaf(dw * rstd, g4.w, b4.w) + rw;
  if (OBF16) {
    uint2 u; u.x = cvtpk(ox, oy); u.y = cvtpk(oz, ow);
    *(uint2*)&((short*)outv)[base] = u;
  } else {
    *(float4*)&((float*)outv)[base] = make_float4(ox, oy, oz, ow);
  }
}

extern "C" void kernel_launch(void* const* d_in, const int* in_sizes, int n_in,
                              void* d_out, int out_size, void* d_ws, size_t ws_size,
                              hipStream_t stream) {
  const float* Xt    = (const float*)d_in[0];
  const float* oMask = (const float*)d_in[1];
  const float* Xe    = (const float*)d_in[2];
  const float* iMask = (const float*)d_in[3];
  const float* Wq1   = (const float*)d_in[4];
  const float* Wk1   = (const float*)d_in[5];
  const float* Wv1   = (const float*)d_in[6];
  const float* Wo1   = (const float*)d_in[7];
  const float* Wq2   = (const float*)d_in[8];
  const float* Wk2   = (const float*)d_in[9];
  const float* Wv2   = (const float*)d_in[10];
  const float* Wo2   = (const float*)d_in[11];
  const float* W1    = (const float*)d_in[12];
  const float* W2    = (const float*)d_in[13];
  const float* g1    = (const float*)d_in[14];
  const float* b1    = (const float*)d_in[15];
  const float* g2    = (const float*)d_in[16];
  const float* b2    = (const float*)d_in[17];
  const float* g3    = (const float*)d_in[18];
  const float* b3    = (const float*)d_in[19];

  const int B = 16, T = 1024, S = 1024;
  const int NT = B * T;
  const size_t SZ = (size_t)NT * 256;   // fp32-sized slot

  float* ws = (float*)d_ws;
  float* s0 = ws;                // Q1/Q2 bf16, FFN H bf16 (spans s0..s1), Wo out bf16
  float* s1 = ws + SZ;           // K bf16
  float* s2 = ws + 2 * SZ;       // V^T tiled bf16
  float* s3 = ws + 3 * SZ;       // attn out bf16
  float* s4 = ws + 4 * SZ;       // Xa bf16 / F bf16
  float* s5 = ws + 5 * SZ;       // Xb bf16
  short* b_s0 = (short*)s0; short* b_s1 = (short*)s1; short* b_s2 = (short*)s2;
  short* b_s3 = (short*)s3; short* b_s4 = (short*)s4; short* b_s5 = (short*)s5;

  dim3 blk(256);
  dim3 gQKV(NT / 128, 2, 3);
  dim3 gKV(NT / 128, 2, 2);
  dim3 gP1(NT / 128, 2, 1);
  dim3 gF1(NT / 128, 8, 1);
  dim3 gAs(T / 128, B * H_);
  dim3 gAc(T / 64, B * H_);

  // ---- self-attention block ----
  gemm_mfma<false, true, false, true><<<gQKV, blk, 0, stream>>>(
      Xt, Xt, Xt, Wq1, Wk1, Wv1, s0, s1, s2, NT, 256, 256, 2);
  attn_mfma<true><<<gAs, blk, 0, stream>>>(b_s0, b_s1, b_s2, oMask, b_s3, T, T);
  gemm_mfma<true, true, false, true><<<gP1, blk, 0, stream>>>(
      s3, s3, s3, Wo1, Wo1, Wo1, s0, s0, s0, NT, 256, 256, -1);
  ln_res<false, true><<<NT / 4, blk, 0, stream>>>(b_s0, Xt, g1, b1, b_s4);

  // ---- cross-attention block ----
  gemm_mfma<true, true, false, true><<<gP1, blk, 0, stream>>>(
      s4, s4, s4, Wq2, Wq2, Wq2, s0, s0, s0, NT, 256, 256, -1);
  gemm_mfma<false, true, false, true><<<gKV, blk, 0, stream>>>(
      Xe, Xe, Xe, Wk2, Wv2, Wv2, s1, s2, s2, NT, 256, 256, 1);
  attn_mfma<false><<<gAc, blk, 0, stream>>>(b_s0, b_s1, b_s2, iMask, b_s3, T, S);
  gemm_mfma<true, false, false, true><<<gP1, blk, 0, stream>>>(
      s3, s3, s3, Wo2, Wo2, Wo2, s0, s0, s0, NT, 256, 256, -1);
  ln_res<true, true><<<NT / 4, blk, 0, stream>>>(b_s0, b_s4, g2, b2, b_s5);

  // ---- FFN ----  (H bf16 spans s0..s1)
  gemm_mfma<true, true, true, true><<<gF1, blk, 0, stream>>>(
      s5, s5, s5, W1, W1, W1, s0, s0, s0, NT, 256, 1024, -1);
  gemm_mfma<true, true, true, true><<<gP1, blk, 0, stream>>>(
      s0, s0, s0, W2, W2, W2, s4, s4, s4, NT, 1024, 256, -1);
  ln_res<true, false><<<NT / 4, blk, 0, stream>>>(b_s4, b_s5, g3, b3, (float*)d_out);
}